// Round 5
// baseline (5008.514 us; speedup 1.0000x reference)
//
#include <hip/hip_runtime.h>
#include <cstddef>
#include <cstdint>

#define BN_EPS 1e-5f

typedef float f4 __attribute__((ext_vector_type(4)));
typedef float f32x4 __attribute__((ext_vector_type(4)));
typedef _Float16 h2 __attribute__((ext_vector_type(2)));
typedef _Float16 h8 __attribute__((ext_vector_type(8)));

#if defined(__has_builtin)
#if __has_builtin(__builtin_amdgcn_fdot2)
#define DOT2(a, b, c) __builtin_amdgcn_fdot2((a), (b), (c), false)
#endif
#endif
#ifndef DOT2
#define DOT2(a, b, c) fmaf((float)(a)[1], (float)(b)[1], fmaf((float)(a)[0], (float)(b)[0], (c)))
#endif

// ---------------------------------------------------------------------------
// fp32 weight transpose (sconv0 only): W[27][CIN][COUT] -> Wt[k][ci/4][co][4]
// ---------------------------------------------------------------------------
template<int CIN, int COUT>
__global__ __launch_bounds__(256)
void wtrans(const float* __restrict__ W, float* __restrict__ Wt)
{
    const int t = blockIdx.x * 256 + threadIdx.x;
    constexpr int TOTAL = 27 * (CIN / 4) * COUT;
    if (t >= TOTAL) return;
    const int co = t % COUT;
    const int rest = t / COUT;
    const int c4 = rest % (CIN / 4);
    const int k  = rest / (CIN / 4);
    f4 v;
    #pragma unroll
    for (int u = 0; u < 4; ++u)
        v[u] = W[((size_t)k * CIN + c4 * 4 + u) * COUT + co];
    *(f4*)(Wt + (size_t)t * 4) = v;
}

// ---------------------------------------------------------------------------
// f16 weight transpose (sconv_r1): W[27][CIN][COUT] -> Wh[k][ci/8][co][8]
// ---------------------------------------------------------------------------
template<int CIN, int COUT>
__global__ __launch_bounds__(256)
void wtrans_h(const float* __restrict__ W, _Float16* __restrict__ Wh)
{
    const int t = blockIdx.x * 256 + threadIdx.x;
    constexpr int TOTAL = 27 * (CIN / 8) * COUT;
    if (t >= TOTAL) return;
    const int co = t % COUT;
    const int rest = t / COUT;
    const int t8 = rest % (CIN / 8);
    const int k  = rest / (CIN / 8);
    h8 v;
    #pragma unroll
    for (int u = 0; u < 8; ++u)
        v[u] = (_Float16)W[((size_t)k * CIN + t8 * 8 + u) * COUT + co];
    *(h8*)(Wh + (size_t)t * 8) = v;
}

// ---------------------------------------------------------------------------
// MFMA weight transform: W[27][CIN][COUT] fp32 -> B-fragment layout f16:
// Wm[((k*NT + t)*NC + ct)*64 + lane][8], h8 holds B[kk][co] with
// kk = t*32 + (lane>>4)*8 + u, co = ct*16 + (lane&15).
// ---------------------------------------------------------------------------
template<int CIN, int COUT>
__global__ __launch_bounds__(256)
void wtrans_mf(const float* __restrict__ W, _Float16* __restrict__ Wm)
{
    constexpr int NT = CIN / 32;
    constexpr int NC = COUT / 16;
    const int t = blockIdx.x * 256 + threadIdx.x;
    constexpr int TOTAL = 27 * NT * NC * 64;
    if (t >= TOTAL) return;
    const int lane = t & 63;
    int rest = t >> 6;
    const int ct = rest % NC; rest /= NC;
    const int tt = rest % NT;
    const int k  = rest / NT;
    const int cin0 = tt * 32 + (lane >> 4) * 8;
    const int co   = ct * 16 + (lane & 15);
    h8 v;
    #pragma unroll
    for (int u = 0; u < 8; ++u)
        v[u] = (_Float16)W[((size_t)k * CIN + cin0 + u) * COUT + co];
    *(h8*)(Wm + (size_t)t * 8) = v;
}

// ---------------------------------------------------------------------------
// Map transpose: map[27][Nout] -> mapT[Nout][32] (k-major per row, -1 pad).
// ---------------------------------------------------------------------------
__global__ __launch_bounds__(256)
void map_transpose(const int* __restrict__ map, int Nout,
                   int* __restrict__ mapT)
{
    __shared__ int s[256][28];
    const int tid  = threadIdx.x;
    const int base = blockIdx.x * 256;
    const int j    = base + tid;
    for (int k = 0; k < 27; ++k)
        s[tid][k] = (j < Nout) ? map[(size_t)k * Nout + j] : -1;
    __syncthreads();
    for (int i = tid; i < 256 * 32; i += 256) {
        const int r = i >> 5, c = i & 31;
        if (base + r < Nout)
            mapT[(size_t)(base + r) * 32 + c] = (c < 27) ? s[r][c] : -1;
    }
}

// ---------------------------------------------------------------------------
// Map transpose + parity-class histogram. For parity-gated maps any set bit
// k reveals the full per-dim parity class: d-component 0 -> even, +-1 -> odd.
// class = ((dx!=0)<<2)|((dy!=0)<<1)|(dz!=0); empty rows -> class 8.
// counts[9] must be pre-zeroed. Grouping is a pure perf heuristic --
// correctness never depends on the parity assumption.
// ---------------------------------------------------------------------------
__global__ __launch_bounds__(256)
void map_transpose_cls(const int* __restrict__ map, int Nout,
                       int* __restrict__ mapT, unsigned char* __restrict__ cls,
                       int* __restrict__ counts)
{
    __shared__ int s[256][28];
    const int tid  = threadIdx.x;
    const int base = blockIdx.x * 256;
    const int j    = base + tid;
    for (int k = 0; k < 27; ++k)
        s[tid][k] = (j < Nout) ? map[(size_t)k * Nout + j] : -1;
    __syncthreads();
    for (int i = tid; i < 256 * 32; i += 256) {
        const int r = i >> 5, c = i & 31;
        if (base + r < Nout)
            mapT[(size_t)(base + r) * 32 + c] = (c < 31) ? ((c < 27) ? s[r][c] : -1) : -1;
    }
    if (j < Nout) {
        int c9 = 8;
        #pragma unroll 1
        for (int k = 0; k < 27; ++k) {
            if (s[tid][k] >= 0) {
                const int dz = k % 3, dy = (k / 3) % 3, dx = k / 9;
                c9 = ((dx != 1) << 2) | ((dy != 1) << 1) | (int)(dz != 1);
                break;
            }
        }
        cls[j] = (unsigned char)c9;
        atomicAdd(&counts[c9], 1);
    }
}

// ---------------------------------------------------------------------------
// Scatter rows into class-grouped order[]: each thread computes the 9-entry
// exclusive prefix from counts (uniform, cached) and appends its row.
// cursors[9] must be pre-zeroed.
// ---------------------------------------------------------------------------
__global__ __launch_bounds__(256)
void scatter_order(const unsigned char* __restrict__ cls, int Nout,
                   const int* __restrict__ counts, int* __restrict__ cursors,
                   int* __restrict__ order)
{
    const int j = blockIdx.x * 256 + threadIdx.x;
    if (j >= Nout) return;
    int offs[9];
    int acc = 0;
    #pragma unroll
    for (int c = 0; c < 9; ++c) { offs[c] = acc; acc += counts[c]; }
    const int c = cls[j];
    const int pos = atomicAdd(&cursors[c], 1);
    order[offs[c] + pos] = j;
}

// ---------------------------------------------------------------------------
// R=1 f16 sparse conv (SPARSE maps): one wave = one row.
// ---------------------------------------------------------------------------
template<int CIN, int CINA, int COUT>
__global__ __launch_bounds__(256)
void sconv_r1(const _Float16* __restrict__ xA, const _Float16* __restrict__ xB,
              const _Float16* __restrict__ Wh, const int* __restrict__ mapT,
              int Nout, _Float16* __restrict__ out)
{
    constexpr int CINB = CIN - CINA;
    constexpr int CPL  = COUT / 64;
    constexpr int NT   = CIN / 8;
    const int lane = threadIdx.x & 63;
    const int j    = blockIdx.x * 4 + (threadIdx.x >> 6);

    int mk = -1;
    if (j < Nout && lane < 32) mk = mapT[(size_t)j * 32 + lane];
    unsigned long long act = __ballot(mk >= 0);   // bits 0..26 only

    float acc[CPL];
    #pragma unroll
    for (int c = 0; c < CPL; ++c) acc[c] = 0.f;

    while (act) {
        const int k = (int)__builtin_ctzll(act);
        act &= act - 1;
        const int m = __builtin_amdgcn_readlane(mk, k);   // uniform SGPR

        const _Float16* pA = xA + (size_t)m * CINA;
        const _Float16* pB = nullptr;
        if constexpr (CINB > 0) pB = xB + (size_t)m * CINB;

        const _Float16* Wk = Wh + (size_t)k * NT * COUT * 8;

        #pragma unroll
        for (int t = 0; t < NT; ++t) {
            const int ci = t * 8;
            h8 wv[CPL];
            #pragma unroll
            for (int c = 0; c < CPL; ++c)
                wv[c] = *(const h8*)(Wk + ((size_t)t * COUT + c * 64 + lane) * 8);
            const _Float16* p;
            if constexpr (CINB > 0)
                p = (ci < CINA) ? (pA + ci) : (pB + (ci - CINA));
            else
                p = pA + ci;
            const h8 xv = *(const h8*)p;
            const h2* xp = (const h2*)&xv;
            #pragma unroll
            for (int q = 0; q < 4; ++q) {
                #pragma unroll
                for (int c = 0; c < CPL; ++c) {
                    const h2* wp = (const h2*)&wv[c];
                    acc[c] = DOT2(xp[q], wp[q], acc[c]);
                }
            }
        }
    }

    if (j < Nout) {
        #pragma unroll
        for (int c = 0; c < CPL; ++c)
            out[(size_t)j * COUT + c * 64 + lane] = (_Float16)acc[c];
    }
}

// ---------------------------------------------------------------------------
// MFMA sparse conv (UNGROUPED, raw map): one wave = 16 consecutive rows.
// Used for block2 (non-parity-gated map). LDS-staged map + 1-deep pipeline.
// ---------------------------------------------------------------------------
template<int CIN, int CINA, int COUT>
__global__ __launch_bounds__(256)
void sconv_mf(const _Float16* __restrict__ xA, const _Float16* __restrict__ xB,
              const _Float16* __restrict__ Wm, const int* __restrict__ map,
              int Nout, _Float16* __restrict__ out,
              const _Float16* __restrict__ zrh)
{
    constexpr int CINB = CIN - CINA;
    constexpr int NT = CIN / 32;
    constexpr int NC = COUT / 16;
    static_assert(CINA % 32 == 0, "CINA must be a multiple of 32");
    const int lane = threadIdx.x & 63;
    const int wave = threadIdx.x >> 6;
    const int row0 = (blockIdx.x * 4 + wave) * 16;

    __shared__ int smap[4][16][28];

    int mk[16];
    bool anyv = false;
    #pragma unroll
    for (int r = 0; r < 16; ++r) {
        const int j = row0 + r;
        mk[r] = (lane < 27 && j < Nout) ? map[(size_t)lane * Nout + j] : -1;
        anyv |= (mk[r] >= 0);
    }
    unsigned long long act = __ballot(anyv);

    if (lane < 27) {
        #pragma unroll
        for (int r = 0; r < 16; ++r)
            smap[wave][r][lane] = mk[r];
    }

    f32x4 acc[NC];
    #pragma unroll
    for (int c = 0; c < NC; ++c) acc[c] = (f32x4){0.f, 0.f, 0.f, 0.f};

    const int rrow = lane & 15;
    const int kseg = lane >> 4;

    auto loada = [&](int k, h8* a) {
        const int m = smap[wave][rrow][k];
        #pragma unroll
        for (int t = 0; t < NT; ++t) {
            const int cin0 = t * 32 + kseg * 8;
            const _Float16* pa;
            if (m >= 0) {
                if (CINB > 0 && t * 32 >= CINA)
                    pa = xB + (size_t)m * CINB + (cin0 - CINA);
                else
                    pa = xA + (size_t)m * CINA + cin0;
            } else {
                pa = zrh;
            }
            a[t] = *(const h8*)pa;
        }
    };
    auto compute = [&](int k, const h8* a) {
        const _Float16* Wk = Wm + ((size_t)k * NT * NC * 64 + lane) * 8;
        #pragma unroll
        for (int t = 0; t < NT; ++t) {
            #pragma unroll
            for (int c = 0; c < NC; ++c) {
                const h8 b = *(const h8*)(Wk + (size_t)(t * NC + c) * 64 * 8);
                acc[c] = __builtin_amdgcn_mfma_f32_16x16x32_f16(a[t], b, acc[c], 0, 0, 0);
            }
        }
    };

    h8 aC[NT], aN[NT];
    int kC = -1;
    if (act) {
        kC = (int)__builtin_ctzll(act);
        act &= act - 1;
        loada(kC, aC);
    }
    while (kC >= 0) {
        int kN = -1;
        if (act) {
            kN = (int)__builtin_ctzll(act);
            act &= act - 1;
            loada(kN, aN);
        }
        compute(kC, aC);
        #pragma unroll
        for (int t = 0; t < NT; ++t) aC[t] = aN[t];
        kC = kN;
    }

    #pragma unroll
    for (int c = 0; c < NC; ++c) {
        #pragma unroll
        for (int r = 0; r < 4; ++r) {
            const int j = row0 + kseg * 4 + r;
            if (j < Nout)
                out[(size_t)j * COUT + c * 16 + rrow] = (_Float16)acc[c][r];
        }
    }
}

// ---------------------------------------------------------------------------
// MFMA sparse conv (GROUPED): wave's 16 rows come from order[] (same parity
// class) so the k-union collapses to the class candidate set (avg ~3.4 vs
// ~22 ungrouped). mapT gives coalesced per-row map reads; outputs scatter
// by true row id. 1-deep pipelined gathers.
// ---------------------------------------------------------------------------
template<int CIN, int CINA, int COUT>
__global__ __launch_bounds__(256)
void sconv_mf_g(const _Float16* __restrict__ xA, const _Float16* __restrict__ xB,
                const _Float16* __restrict__ Wm, const int* __restrict__ mapT,
                const int* __restrict__ order, int Nout,
                _Float16* __restrict__ out, const _Float16* __restrict__ zrh)
{
    constexpr int CINB = CIN - CINA;
    constexpr int NT = CIN / 32;
    constexpr int NC = COUT / 16;
    static_assert(CINA % 32 == 0, "CINA must be a multiple of 32");
    const int lane = threadIdx.x & 63;
    const int wave = threadIdx.x >> 6;
    const int wrow0 = (blockIdx.x * 4 + wave) * 16;

    __shared__ int sjr[4][16];
    __shared__ int smap[4][16][28];   // stride 28: ~2-way bank on reads

    if (lane < 16) {
        const int idx = wrow0 + lane;
        sjr[wave][lane] = (idx < Nout) ? order[idx] : -1;
    }
    // wave-local LDS RAW: compiler-inserted lgkmcnt orders it (no barrier).
    const int kk = lane & 31;
    bool anyv = false;
    #pragma unroll
    for (int r = 0; r < 16; ++r) {
        const int jr = sjr[wave][r];
        int v = -1;
        if (jr >= 0 && kk < 27) v = mapT[(size_t)jr * 32 + kk];
        if (lane < 28) smap[wave][r][lane] = v;
        anyv |= (v >= 0);
    }
    const unsigned long long bal = __ballot(anyv);
    unsigned long long act = (bal | (bal >> 32)) & 0x7FFFFFFull;

    f32x4 acc[NC];
    #pragma unroll
    for (int c = 0; c < NC; ++c) acc[c] = (f32x4){0.f, 0.f, 0.f, 0.f};

    const int rrow = lane & 15;
    const int kseg = lane >> 4;

    auto loada = [&](int k, h8* a) {
        const int m = smap[wave][rrow][k];
        #pragma unroll
        for (int t = 0; t < NT; ++t) {
            const int cin0 = t * 32 + kseg * 8;
            const _Float16* pa;
            if (m >= 0) {
                if (CINB > 0 && t * 32 >= CINA)
                    pa = xB + (size_t)m * CINB + (cin0 - CINA);
                else
                    pa = xA + (size_t)m * CINA + cin0;
            } else {
                pa = zrh;
            }
            a[t] = *(const h8*)pa;
        }
    };
    auto compute = [&](int k, const h8* a) {
        const _Float16* Wk = Wm + ((size_t)k * NT * NC * 64 + lane) * 8;
        #pragma unroll
        for (int t = 0; t < NT; ++t) {
            #pragma unroll
            for (int c = 0; c < NC; ++c) {
                const h8 b = *(const h8*)(Wk + (size_t)(t * NC + c) * 64 * 8);
                acc[c] = __builtin_amdgcn_mfma_f32_16x16x32_f16(a[t], b, acc[c], 0, 0, 0);
            }
        }
    };

    h8 aC[NT], aN[NT];
    int kC = -1;
    if (act) {
        kC = (int)__builtin_ctzll(act);
        act &= act - 1;
        loada(kC, aC);
    }
    while (kC >= 0) {
        int kN = -1;
        if (act) {
            kN = (int)__builtin_ctzll(act);
            act &= act - 1;
            loada(kN, aN);
        }
        compute(kC, aC);
        #pragma unroll
        for (int t = 0; t < NT; ++t) aC[t] = aN[t];
        kC = kN;
    }

    #pragma unroll
    for (int c = 0; c < NC; ++c) {
        #pragma unroll
        for (int r = 0; r < 4; ++r) {
            const int j = sjr[wave][kseg * 4 + r];
            if (j >= 0)
                out[(size_t)j * COUT + c * 16 + rrow] = (_Float16)acc[c][r];
        }
    }
}

// ---------------------------------------------------------------------------
// conv0: CIN=16 (fp32 feats), COUT=32 -> half out. 2 rows/wave, ctz-union.
// ---------------------------------------------------------------------------
__global__ __launch_bounds__(256)
void sconv0(const float* __restrict__ x, const float* __restrict__ Wt,
            const int* __restrict__ map, int N, _Float16* __restrict__ out,
            const float* __restrict__ zrow)
{
    const int tid  = threadIdx.x;
    const int lane = tid & 63;
    const int l32  = tid & 31;
    const int co   = l32;
    const int j    = blockIdx.x * 8 + (tid >> 5);

    int mk = (l32 < 27 && j < N) ? map[(size_t)l32 * N + j] : -1;
    const unsigned long long bal = __ballot(mk >= 0);
    unsigned int act = (unsigned int)((bal | (bal >> 32)) & 0x7FFFFFFu);

    float a0 = 0.f, a1 = 0.f, a2 = 0.f, a3 = 0.f;
    while (act) {
        const int k = (int)__builtin_ctz(act);
        act &= act - 1;
        const int m = __shfl(mk, (lane & 32) + k);
        const float* xr = (m >= 0) ? (x + (size_t)m * 16) : zrow;
        const float* wk = Wt + (size_t)k * 16 * 32;
        f4 w0 = *(const f4*)(wk + (0 * 32 + co) * 4);
        f4 w1 = *(const f4*)(wk + (1 * 32 + co) * 4);
        f4 w2 = *(const f4*)(wk + (2 * 32 + co) * 4);
        f4 w3 = *(const f4*)(wk + (3 * 32 + co) * 4);
        f4 x0 = *(const f4*)(xr);
        f4 x1 = *(const f4*)(xr + 4);
        f4 x2 = *(const f4*)(xr + 8);
        f4 x3 = *(const f4*)(xr + 12);
        #pragma unroll
        for (int u = 0; u < 4; ++u) {
            a0 = fmaf(x0[u], w0[u], a0);
            a1 = fmaf(x1[u], w1[u], a1);
            a2 = fmaf(x2[u], w2[u], a2);
            a3 = fmaf(x3[u], w3[u], a3);
        }
    }
    if (j < N) out[(size_t)j * 32 + co] = (_Float16)((a0 + a1) + (a2 + a3));
}

// ---------------------------------------------------------------------------
// conv0t: concat(d1[*,64]h, s1[*,32]h) -> out[N0,2] fp32. ctz-union loop.
// ---------------------------------------------------------------------------
__global__ __launch_bounds__(256)
void sconv0t(const _Float16* __restrict__ d1, const _Float16* __restrict__ s1,
             const float* __restrict__ W /*[27,96,2]*/,
             const int* __restrict__ map, int N, float* __restrict__ out,
             const _Float16* __restrict__ zrh)
{
    const int tid  = threadIdx.x;
    const int lane = tid & 63;
    const int l32  = tid & 31;
    const int j    = blockIdx.x * 8 + (tid >> 5);

    int mk = (l32 < 27 && j < N) ? map[(size_t)l32 * N + j] : -1;
    const unsigned long long bal = __ballot(mk >= 0);
    unsigned int act = (unsigned int)((bal | (bal >> 32)) & 0x7FFFFFFu);

    float a0 = 0.f, a1 = 0.f;
    while (act) {
        const int k = (int)__builtin_ctz(act);
        act &= act - 1;
        const int m = __shfl(mk, (lane & 32) + k);
        const _Float16* p1 = (m >= 0) ? (d1 + (size_t)m * 64) : zrh;
        const _Float16* p2 = (m >= 0) ? (s1 + (size_t)m * 32) : zrh;
        const float* w = W + (size_t)k * 96 * 2;
        const float x0 = (float)p1[l32];
        const float x1 = (float)p1[l32 + 32];
        const float x2 = (float)p2[l32];
        a0 = fmaf(x0, w[l32 * 2 + 0], a0);
        a1 = fmaf(x0, w[l32 * 2 + 1], a1);
        a0 = fmaf(x1, w[(l32 + 32) * 2 + 0], a0);
        a1 = fmaf(x1, w[(l32 + 32) * 2 + 1], a1);
        a0 = fmaf(x2, w[(l32 + 64) * 2 + 0], a0);
        a1 = fmaf(x2, w[(l32 + 64) * 2 + 1], a1);
    }
    #pragma unroll
    for (int off = 1; off < 32; off <<= 1) {
        a0 += __shfl_xor(a0, off, 32);
        a1 += __shfl_xor(a1, off, 32);
    }
    if (l32 == 0 && j < N) {
        out[(size_t)j * 2 + 0] = a0;
        out[(size_t)j * 2 + 1] = a1;
    }
}

// ---------------------------------------------------------------------------
// BN pass 1 on half tensors
// ---------------------------------------------------------------------------
template<int C>
__global__ __launch_bounds__(256)
void bn_reduce_h(const _Float16* __restrict__ x, int N,
                 float* __restrict__ sums)
{
    constexpr int RG = 256 / C;
    const int tid = threadIdx.x;
    const int c   = tid % C;
    const int rg  = tid / C;
    float s = 0.f, s2 = 0.f;
    for (int j = blockIdx.x * RG + rg; j < N; j += gridDim.x * RG) {
        const float v = (float)x[(size_t)j * C + c];
        s += v;
        s2 += v * v;
    }
    __shared__ float sh[2 * 256];
    sh[tid] = s;
    sh[256 + tid] = s2;
    __syncthreads();
    for (int stride = 128; stride >= C; stride >>= 1) {
        if (tid < stride) {
            sh[tid] += sh[tid + stride];
            sh[256 + tid] += sh[256 + tid + stride];
        }
        __syncthreads();
    }
    if (tid < C) {
        atomicAdd(&sums[c], sh[tid]);
        atomicAdd(&sums[C + c], sh[256 + tid]);
    }
}

// ---------------------------------------------------------------------------
// BN pass 2 on half tensors
// ---------------------------------------------------------------------------
template<int C>
__global__ __launch_bounds__(256)
void bn_apply_h(_Float16* __restrict__ x, int N,
                const float* __restrict__ sums,
                const float* __restrict__ g, const float* __restrict__ b)
{
    const int tid = blockIdx.x * blockDim.x + threadIdx.x;
    const int c = tid % C;
    const float invN = 1.0f / (float)N;
    const float mean = sums[c] * invN;
    float var = sums[C + c] * invN - mean * mean;
    var = fmaxf(var, 0.f);
    const float sc = g[c] * rsqrtf(var + BN_EPS);
    const float sh = b[c] - mean * sc;
    const int rows_stride = (gridDim.x * blockDim.x) / C;
    for (int j = tid / C; j < N; j += rows_stride) {
        const size_t i = (size_t)j * C + c;
        const float v = fmaf((float)x[i], sc, sh);
        x[i] = (_Float16)(v > 0.f ? v : 0.f);
    }
}

// ---------------------------------------------------------------------------
extern "C" void kernel_launch(void* const* d_in, const int* in_sizes, int n_in,
                              void* d_out, int out_size, void* d_ws, size_t ws_size,
                              hipStream_t stream)
{
    const float* feats = (const float*)d_in[0];
    const float* W0  = (const float*)d_in[1];
    const float* g0  = (const float*)d_in[2];
    const float* b0  = (const float*)d_in[3];
    const float* W1  = (const float*)d_in[4];
    const float* g1  = (const float*)d_in[5];
    const float* b1  = (const float*)d_in[6];
    const float* W2  = (const float*)d_in[7];
    const float* g2  = (const float*)d_in[8];
    const float* b2  = (const float*)d_in[9];
    const float* W2t = (const float*)d_in[10];
    const float* g2t = (const float*)d_in[11];
    const float* b2t = (const float*)d_in[12];
    const float* W1t = (const float*)d_in[13];
    const float* g1t = (const float*)d_in[14];
    const float* b1t = (const float*)d_in[15];
    const float* W0t = (const float*)d_in[16];
    const int* map0  = (const int*)d_in[17];
    const int* map1  = (const int*)d_in[18];
    const int* map2  = (const int*)d_in[19];
    const int* map2t = (const int*)d_in[20];
    const int* map1t = (const int*)d_in[21];
    const int* map0t = (const int*)d_in[22];

    const int N0 = in_sizes[0] / 16;
    const int N1 = in_sizes[18] / 27;
    const int N2 = in_sizes[19] / 27;

    float* ws = (float*)d_ws;
    float* sums  = ws;          // 704 floats of BN accumulators
    float* sums0 = sums;        // 2*32
    float* sums1 = sums + 64;   // 2*64
    float* sums2 = sums + 192;  // 2*128
    float* sums3 = sums + 448;  // 2*64
    float* sums4 = sums + 576;  // 2*64
    float* zrow  = sums + 704;  // 128 zeroed floats (fp32 & f16 zero rows)
    int*   gcnt  = (int*)(zrow + 128);  // 64 ints: 2x {counts[9], cursors[9]} regions
    float* Wt0   = (float*)(gcnt + 64); // 27*16*32 fp32
    _Float16* hb = (_Float16*)(Wt0 + 27 * 16 * 32);
    _Float16* Wh1  = hb;                        // 27*32*64
    _Float16* Wh2  = Wh1 + 27 * 32 * 64;        // 27*64*128  (MFMA layout)
    _Float16* Wh2t = Wh2 + 27 * 64 * 128;       // 27*128*64  (MFMA layout)
    _Float16* Wh1t = Wh2t + 27 * 128 * 64;      // 27*128*64  (MFMA layout)
    _Float16* y0 = Wh1t + 27 * 128 * 64;        // [N0,32]  s1
    _Float16* y1 = y0 + (size_t)N0 * 32;        // [N1,64]  s2
    _Float16* y2 = y1 + (size_t)N1 * 64;        // [N2,128] s4
    _Float16* y3 = y2 + (size_t)N2 * 128;       // [N1,64]  d2
    _Float16* y4 = y3 + (size_t)N1 * 64;        // [N0,64]  d1
    int* mapT = (int*)(y4 + (size_t)N0 * 64);   // [Nmax,32] transposed map
    int* order = mapT + (size_t)N0 * 32;        // [Nmax] grouped row ids
    unsigned char* clsb = (unsigned char*)(order + N0);  // [Nmax] classes
    const _Float16* zrh = (const _Float16*)zrow;

    (void)hipMemsetAsync(sums, 0, (704 + 128 + 64) * sizeof(float), stream);

    // weight transposes (tiny)
    wtrans<16, 32><<<(27 * 4 * 32 + 255) / 256, 256, 0, stream>>>(W0, Wt0);
    wtrans_h<32, 64><<<(27 * 4 * 64 + 255) / 256, 256, 0, stream>>>(W1, Wh1);
    wtrans_mf<64, 128><<<(27 * 2 * 8 * 64 + 255) / 256, 256, 0, stream>>>(W2, Wh2);
    wtrans_mf<128, 64><<<(27 * 4 * 4 * 64 + 255) / 256, 256, 0, stream>>>(W2t, Wh2t);
    wtrans_mf<128, 64><<<(27 * 4 * 4 * 64 + 255) / 256, 256, 0, stream>>>(W1t, Wh1t);

    // block0: feats[N0,16] fp32 -> y0[N0,32] half
    sconv0<<<(N0 + 7) / 8, 256, 0, stream>>>(feats, Wt0, map0, N0, y0, zrow);
    bn_reduce_h<32><<<256, 256, 0, stream>>>(y0, N0, sums0);
    bn_apply_h<32><<<512, 256, 0, stream>>>(y0, N0, sums0, g0, b0);

    // block1 (SPARSE map): one wave per row (scalar dot2 path)
    map_transpose<<<(N1 + 255) / 256, 256, 0, stream>>>(map1, N1, mapT);
    sconv_r1<32, 32, 64><<<(N1 + 3) / 4, 256, 0, stream>>>(
        y0, nullptr, Wh1, mapT, N1, y1);
    bn_reduce_h<64><<<256, 256, 0, stream>>>(y1, N1, sums1);
    bn_apply_h<64><<<512, 256, 0, stream>>>(y1, N1, sums1, g1, b1);

    // block2: MFMA ungrouped (map2 not parity-gated)
    sconv_mf<64, 64, 128><<<(N2 + 63) / 64, 256, 0, stream>>>(
        y1, nullptr, Wh2, map2, N2, y2, zrh);
    bn_reduce_h<128><<<256, 256, 0, stream>>>(y2, N2, sums2);
    bn_apply_h<128><<<512, 256, 0, stream>>>(y2, N2, sums2, g2, b2);

    // block2_tr: parity-grouped MFMA (k-union 22 -> ~3.4 per wave)
    map_transpose_cls<<<(N1 + 255) / 256, 256, 0, stream>>>(
        map2t, N1, mapT, clsb, gcnt);
    scatter_order<<<(N1 + 255) / 256, 256, 0, stream>>>(
        clsb, N1, gcnt, gcnt + 9, order);
    sconv_mf_g<128, 128, 64><<<(N1 + 63) / 64, 256, 0, stream>>>(
        y2, nullptr, Wh2t, mapT, order, N1, y3, zrh);
    bn_reduce_h<64><<<256, 256, 0, stream>>>(y3, N1, sums3);
    bn_apply_h<64><<<512, 256, 0, stream>>>(y3, N1, sums3, g2t, b2t);

    // block1_tr: parity-grouped MFMA, concat input (y3[64] ++ y1[64])
    map_transpose_cls<<<(N0 + 255) / 256, 256, 0, stream>>>(
        map1t, N0, mapT, clsb, gcnt + 32);
    scatter_order<<<(N0 + 255) / 256, 256, 0, stream>>>(
        clsb, N0, gcnt + 32, gcnt + 32 + 9, order);
    sconv_mf_g<128, 64, 64><<<(N0 + 63) / 64, 256, 0, stream>>>(
        y3, y1, Wh1t, mapT, order, N0, y4, zrh);
    bn_reduce_h<64><<<256, 256, 0, stream>>>(y4, N0, sums4);
    bn_apply_h<64><<<512, 256, 0, stream>>>(y4, N0, sums4, g1t, b1t);

    // block0_tr: concat(d1,s1)[N0,96] -> out[N0,2] fp32
    sconv0t<<<(N0 + 7) / 8, 256, 0, stream>>>(y4, y0, W0t, map0t, N0,
                                              (float*)d_out, zrh);
}

// Round 6
// 932.807 us; speedup vs baseline: 5.3693x; 5.3693x over previous
//
#include <hip/hip_runtime.h>
#include <cstddef>
#include <cstdint>

#define BN_EPS 1e-5f

typedef float f4 __attribute__((ext_vector_type(4)));
typedef float f32x4 __attribute__((ext_vector_type(4)));
typedef _Float16 h2 __attribute__((ext_vector_type(2)));
typedef _Float16 h8 __attribute__((ext_vector_type(8)));

#if defined(__has_builtin)
#if __has_builtin(__builtin_amdgcn_fdot2)
#define DOT2(a, b, c) __builtin_amdgcn_fdot2((a), (b), (c), false)
#endif
#endif
#ifndef DOT2
#define DOT2(a, b, c) fmaf((float)(a)[1], (float)(b)[1], fmaf((float)(a)[0], (float)(b)[0], (c)))
#endif

// ---------------------------------------------------------------------------
// fp32 weight transpose (sconv0 only): W[27][CIN][COUT] -> Wt[k][ci/4][co][4]
// ---------------------------------------------------------------------------
template<int CIN, int COUT>
__global__ __launch_bounds__(256)
void wtrans(const float* __restrict__ W, float* __restrict__ Wt)
{
    const int t = blockIdx.x * 256 + threadIdx.x;
    constexpr int TOTAL = 27 * (CIN / 4) * COUT;
    if (t >= TOTAL) return;
    const int co = t % COUT;
    const int rest = t / COUT;
    const int c4 = rest % (CIN / 4);
    const int k  = rest / (CIN / 4);
    f4 v;
    #pragma unroll
    for (int u = 0; u < 4; ++u)
        v[u] = W[((size_t)k * CIN + c4 * 4 + u) * COUT + co];
    *(f4*)(Wt + (size_t)t * 4) = v;
}

// ---------------------------------------------------------------------------
// f16 weight transpose (sconv_r1): W[27][CIN][COUT] -> Wh[k][ci/8][co][8]
// ---------------------------------------------------------------------------
template<int CIN, int COUT>
__global__ __launch_bounds__(256)
void wtrans_h(const float* __restrict__ W, _Float16* __restrict__ Wh)
{
    const int t = blockIdx.x * 256 + threadIdx.x;
    constexpr int TOTAL = 27 * (CIN / 8) * COUT;
    if (t >= TOTAL) return;
    const int co = t % COUT;
    const int rest = t / COUT;
    const int t8 = rest % (CIN / 8);
    const int k  = rest / (CIN / 8);
    h8 v;
    #pragma unroll
    for (int u = 0; u < 8; ++u)
        v[u] = (_Float16)W[((size_t)k * CIN + t8 * 8 + u) * COUT + co];
    *(h8*)(Wh + (size_t)t * 8) = v;
}

// ---------------------------------------------------------------------------
// MFMA weight transform: W[27][CIN][COUT] fp32 -> B-fragment layout f16:
// Wm[((k*NT + t)*NC + ct)*64 + lane][8], h8 holds B[kk][co] with
// kk = t*32 + (lane>>4)*8 + u, co = ct*16 + (lane&15).
// ---------------------------------------------------------------------------
template<int CIN, int COUT>
__global__ __launch_bounds__(256)
void wtrans_mf(const float* __restrict__ W, _Float16* __restrict__ Wm)
{
    constexpr int NT = CIN / 32;
    constexpr int NC = COUT / 16;
    const int t = blockIdx.x * 256 + threadIdx.x;
    constexpr int TOTAL = 27 * NT * NC * 64;
    if (t >= TOTAL) return;
    const int lane = t & 63;
    int rest = t >> 6;
    const int ct = rest % NC; rest /= NC;
    const int tt = rest % NT;
    const int k  = rest / NT;
    const int cin0 = tt * 32 + (lane >> 4) * 8;
    const int co   = ct * 16 + (lane & 15);
    h8 v;
    #pragma unroll
    for (int u = 0; u < 8; ++u)
        v[u] = (_Float16)W[((size_t)k * CIN + cin0 + u) * COUT + co];
    *(h8*)(Wm + (size_t)t * 8) = v;
}

// ---------------------------------------------------------------------------
// Map transpose: map[27][Nout] -> mapT[Nout][32] (k-major per row, -1 pad).
// ---------------------------------------------------------------------------
__global__ __launch_bounds__(256)
void map_transpose(const int* __restrict__ map, int Nout,
                   int* __restrict__ mapT)
{
    __shared__ int s[256][28];
    const int tid  = threadIdx.x;
    const int base = blockIdx.x * 256;
    const int j    = base + tid;
    for (int k = 0; k < 27; ++k)
        s[tid][k] = (j < Nout) ? map[(size_t)k * Nout + j] : -1;
    __syncthreads();
    for (int i = tid; i < 256 * 32; i += 256) {
        const int r = i >> 5, c = i & 31;
        if (base + r < Nout)
            mapT[(size_t)(base + r) * 32 + c] = (c < 27) ? s[r][c] : -1;
    }
}

// ---------------------------------------------------------------------------
// Map transpose + parity-class GROUPING, contention-free (round-6 fix of the
// round-5 atomic wall: 200k global atomics on 9 addrs = 1.2ms. Now: LDS
// histogram -> 9 global atomics PER BLOCK (~7k total) -> LDS cursors).
// Class regions are fixed at c*Npad in order[] (Npad 16-aligned so waves
// never straddle classes); unfilled slots stay -1 (pre-memset 0xFF).
// Grouping is a pure perf heuristic; correctness is permutation-invariant.
// ---------------------------------------------------------------------------
__global__ __launch_bounds__(256)
void map_transpose_grp(const int* __restrict__ map, int Nout, int Npad,
                       int* __restrict__ mapT, int* __restrict__ gcursor,
                       int* __restrict__ order)
{
    __shared__ int s[256][28];
    __shared__ int hist[9], basec[9], cur[9];
    const int tid  = threadIdx.x;
    const int base = blockIdx.x * 256;
    const int j    = base + tid;
    if (tid < 9) { hist[tid] = 0; cur[tid] = 0; }
    for (int k = 0; k < 27; ++k)
        s[tid][k] = (j < Nout) ? map[(size_t)k * Nout + j] : -1;
    __syncthreads();
    for (int i = tid; i < 256 * 32; i += 256) {
        const int r = i >> 5, c = i & 31;
        if (base + r < Nout)
            mapT[(size_t)(base + r) * 32 + c] = (c < 27) ? s[r][c] : -1;
    }
    int c9 = 8;
    if (j < Nout) {
        #pragma unroll 1
        for (int k = 0; k < 27; ++k) {
            if (s[tid][k] >= 0) {
                const int dz = k % 3, dy = (k / 3) % 3, dx = k / 9;
                c9 = ((dx != 1) << 2) | ((dy != 1) << 1) | (int)(dz != 1);
                break;
            }
        }
        atomicAdd(&hist[c9], 1);
    }
    __syncthreads();
    if (tid < 9 && hist[tid] > 0)
        basec[tid] = atomicAdd(&gcursor[tid], hist[tid]);
    __syncthreads();
    if (j < Nout) {
        const int lpos = atomicAdd(&cur[c9], 1);
        order[(size_t)c9 * Npad + basec[c9] + lpos] = j;
    }
}

// ---------------------------------------------------------------------------
// R=1 f16 sparse conv (SPARSE maps): one wave = one row.
// ---------------------------------------------------------------------------
template<int CIN, int CINA, int COUT>
__global__ __launch_bounds__(256)
void sconv_r1(const _Float16* __restrict__ xA, const _Float16* __restrict__ xB,
              const _Float16* __restrict__ Wh, const int* __restrict__ mapT,
              int Nout, _Float16* __restrict__ out)
{
    constexpr int CINB = CIN - CINA;
    constexpr int CPL  = COUT / 64;
    constexpr int NT   = CIN / 8;
    const int lane = threadIdx.x & 63;
    const int j    = blockIdx.x * 4 + (threadIdx.x >> 6);

    int mk = -1;
    if (j < Nout && lane < 32) mk = mapT[(size_t)j * 32 + lane];
    unsigned long long act = __ballot(mk >= 0);   // bits 0..26 only

    float acc[CPL];
    #pragma unroll
    for (int c = 0; c < CPL; ++c) acc[c] = 0.f;

    while (act) {
        const int k = (int)__builtin_ctzll(act);
        act &= act - 1;
        const int m = __builtin_amdgcn_readlane(mk, k);   // uniform SGPR

        const _Float16* pA = xA + (size_t)m * CINA;
        const _Float16* pB = nullptr;
        if constexpr (CINB > 0) pB = xB + (size_t)m * CINB;

        const _Float16* Wk = Wh + (size_t)k * NT * COUT * 8;

        #pragma unroll
        for (int t = 0; t < NT; ++t) {
            const int ci = t * 8;
            h8 wv[CPL];
            #pragma unroll
            for (int c = 0; c < CPL; ++c)
                wv[c] = *(const h8*)(Wk + ((size_t)t * COUT + c * 64 + lane) * 8);
            const _Float16* p;
            if constexpr (CINB > 0)
                p = (ci < CINA) ? (pA + ci) : (pB + (ci - CINA));
            else
                p = pA + ci;
            const h8 xv = *(const h8*)p;
            const h2* xp = (const h2*)&xv;
            #pragma unroll
            for (int q = 0; q < 4; ++q) {
                #pragma unroll
                for (int c = 0; c < CPL; ++c) {
                    const h2* wp = (const h2*)&wv[c];
                    acc[c] = DOT2(xp[q], wp[q], acc[c]);
                }
            }
        }
    }

    if (j < Nout) {
        #pragma unroll
        for (int c = 0; c < CPL; ++c)
            out[(size_t)j * COUT + c * 64 + lane] = (_Float16)acc[c];
    }
}

// ---------------------------------------------------------------------------
// MFMA sparse conv (UNGROUPED, raw map): one wave = 16 consecutive rows.
// Used for block2 (non-parity-gated map). LDS-staged map + 1-deep pipeline.
// ---------------------------------------------------------------------------
template<int CIN, int CINA, int COUT>
__global__ __launch_bounds__(256)
void sconv_mf(const _Float16* __restrict__ xA, const _Float16* __restrict__ xB,
              const _Float16* __restrict__ Wm, const int* __restrict__ map,
              int Nout, _Float16* __restrict__ out,
              const _Float16* __restrict__ zrh)
{
    constexpr int CINB = CIN - CINA;
    constexpr int NT = CIN / 32;
    constexpr int NC = COUT / 16;
    static_assert(CINA % 32 == 0, "CINA must be a multiple of 32");
    const int lane = threadIdx.x & 63;
    const int wave = threadIdx.x >> 6;
    const int row0 = (blockIdx.x * 4 + wave) * 16;

    __shared__ int smap[4][16][28];

    int mk[16];
    bool anyv = false;
    #pragma unroll
    for (int r = 0; r < 16; ++r) {
        const int j = row0 + r;
        mk[r] = (lane < 27 && j < Nout) ? map[(size_t)lane * Nout + j] : -1;
        anyv |= (mk[r] >= 0);
    }
    unsigned long long act = __ballot(anyv);

    if (lane < 27) {
        #pragma unroll
        for (int r = 0; r < 16; ++r)
            smap[wave][r][lane] = mk[r];
    }

    f32x4 acc[NC];
    #pragma unroll
    for (int c = 0; c < NC; ++c) acc[c] = (f32x4){0.f, 0.f, 0.f, 0.f};

    const int rrow = lane & 15;
    const int kseg = lane >> 4;

    auto loada = [&](int k, h8* a) {
        const int m = smap[wave][rrow][k];
        #pragma unroll
        for (int t = 0; t < NT; ++t) {
            const int cin0 = t * 32 + kseg * 8;
            const _Float16* pa;
            if (m >= 0) {
                if (CINB > 0 && t * 32 >= CINA)
                    pa = xB + (size_t)m * CINB + (cin0 - CINA);
                else
                    pa = xA + (size_t)m * CINA + cin0;
            } else {
                pa = zrh;
            }
            a[t] = *(const h8*)pa;
        }
    };
    auto compute = [&](int k, const h8* a) {
        const _Float16* Wk = Wm + ((size_t)k * NT * NC * 64 + lane) * 8;
        #pragma unroll
        for (int t = 0; t < NT; ++t) {
            #pragma unroll
            for (int c = 0; c < NC; ++c) {
                const h8 b = *(const h8*)(Wk + (size_t)(t * NC + c) * 64 * 8);
                acc[c] = __builtin_amdgcn_mfma_f32_16x16x32_f16(a[t], b, acc[c], 0, 0, 0);
            }
        }
    };

    h8 aC[NT], aN[NT];
    int kC = -1;
    if (act) {
        kC = (int)__builtin_ctzll(act);
        act &= act - 1;
        loada(kC, aC);
    }
    while (kC >= 0) {
        int kN = -1;
        if (act) {
            kN = (int)__builtin_ctzll(act);
            act &= act - 1;
            loada(kN, aN);
        }
        compute(kC, aC);
        #pragma unroll
        for (int t = 0; t < NT; ++t) aC[t] = aN[t];
        kC = kN;
    }

    #pragma unroll
    for (int c = 0; c < NC; ++c) {
        #pragma unroll
        for (int r = 0; r < 4; ++r) {
            const int j = row0 + kseg * 4 + r;
            if (j < Nout)
                out[(size_t)j * COUT + c * 16 + rrow] = (_Float16)acc[c][r];
        }
    }
}

// ---------------------------------------------------------------------------
// MFMA sparse conv (GROUPED): wave's 16 rows come from order[] (same parity
// class -> k-union <= 8 vs <= 27). Slots with -1 (class-region padding) are
// skipped; dead waves exit after the ballot. mapT gives coalesced per-row
// map reads; outputs scatter by true row id. 1-deep pipelined gathers.
// ---------------------------------------------------------------------------
template<int CIN, int CINA, int COUT>
__global__ __launch_bounds__(256)
void sconv_mf_g(const _Float16* __restrict__ xA, const _Float16* __restrict__ xB,
                const _Float16* __restrict__ Wm, const int* __restrict__ mapT,
                const int* __restrict__ order, int NTOT, int Nout,
                _Float16* __restrict__ out, const _Float16* __restrict__ zrh)
{
    constexpr int CINB = CIN - CINA;
    constexpr int NT = CIN / 32;
    constexpr int NC = COUT / 16;
    static_assert(CINA % 32 == 0, "CINA must be a multiple of 32");
    const int lane = threadIdx.x & 63;
    const int wave = threadIdx.x >> 6;
    const int wrow0 = (blockIdx.x * 4 + wave) * 16;

    __shared__ int sjr[4][16];
    __shared__ int smap[4][16][28];   // stride 28: ~2-way bank on reads

    if (lane < 16) {
        const int idx = wrow0 + lane;
        sjr[wave][lane] = (idx < NTOT) ? order[idx] : -1;
    }
    // wave-local LDS RAW: compiler-inserted lgkmcnt orders it (no barrier).
    const int kk = lane & 31;
    bool anyv = false;
    #pragma unroll
    for (int r = 0; r < 16; ++r) {
        const int jr = sjr[wave][r];
        int v = -1;
        if (jr >= 0 && kk < 27) v = mapT[(size_t)jr * 32 + kk];
        if (lane < 28) smap[wave][r][lane] = v;
        anyv |= (v >= 0);
    }
    const unsigned long long bal = __ballot(anyv);
    unsigned long long act = (bal | (bal >> 32)) & 0x7FFFFFFull;

    f32x4 acc[NC];
    #pragma unroll
    for (int c = 0; c < NC; ++c) acc[c] = (f32x4){0.f, 0.f, 0.f, 0.f};

    const int rrow = lane & 15;
    const int kseg = lane >> 4;

    auto loada = [&](int k, h8* a) {
        const int m = smap[wave][rrow][k];
        #pragma unroll
        for (int t = 0; t < NT; ++t) {
            const int cin0 = t * 32 + kseg * 8;
            const _Float16* pa;
            if (m >= 0) {
                if (CINB > 0 && t * 32 >= CINA)
                    pa = xB + (size_t)m * CINB + (cin0 - CINA);
                else
                    pa = xA + (size_t)m * CINA + cin0;
            } else {
                pa = zrh;
            }
            a[t] = *(const h8*)pa;
        }
    };
    auto compute = [&](int k, const h8* a) {
        const _Float16* Wk = Wm + ((size_t)k * NT * NC * 64 + lane) * 8;
        #pragma unroll
        for (int t = 0; t < NT; ++t) {
            #pragma unroll
            for (int c = 0; c < NC; ++c) {
                const h8 b = *(const h8*)(Wk + (size_t)(t * NC + c) * 64 * 8);
                acc[c] = __builtin_amdgcn_mfma_f32_16x16x32_f16(a[t], b, acc[c], 0, 0, 0);
            }
        }
    };

    h8 aC[NT], aN[NT];
    int kC = -1;
    if (act) {
        kC = (int)__builtin_ctzll(act);
        act &= act - 1;
        loada(kC, aC);
    }
    while (kC >= 0) {
        int kN = -1;
        if (act) {
            kN = (int)__builtin_ctzll(act);
            act &= act - 1;
            loada(kN, aN);
        }
        compute(kC, aC);
        #pragma unroll
        for (int t = 0; t < NT; ++t) aC[t] = aN[t];
        kC = kN;
    }

    #pragma unroll
    for (int c = 0; c < NC; ++c) {
        #pragma unroll
        for (int r = 0; r < 4; ++r) {
            const int j = sjr[wave][kseg * 4 + r];
            if (j >= 0)
                out[(size_t)j * COUT + c * 16 + rrow] = (_Float16)acc[c][r];
        }
    }
}

// ---------------------------------------------------------------------------
// conv0: CIN=16 (fp32 feats), COUT=32 -> half out. 2 rows/wave, ctz-union.
// ---------------------------------------------------------------------------
__global__ __launch_bounds__(256)
void sconv0(const float* __restrict__ x, const float* __restrict__ Wt,
            const int* __restrict__ map, int N, _Float16* __restrict__ out,
            const float* __restrict__ zrow)
{
    const int tid  = threadIdx.x;
    const int lane = tid & 63;
    const int l32  = tid & 31;
    const int co   = l32;
    const int j    = blockIdx.x * 8 + (tid >> 5);

    int mk = (l32 < 27 && j < N) ? map[(size_t)l32 * N + j] : -1;
    const unsigned long long bal = __ballot(mk >= 0);
    unsigned int act = (unsigned int)((bal | (bal >> 32)) & 0x7FFFFFFu);

    float a0 = 0.f, a1 = 0.f, a2 = 0.f, a3 = 0.f;
    while (act) {
        const int k = (int)__builtin_ctz(act);
        act &= act - 1;
        const int m = __shfl(mk, (lane & 32) + k);
        const float* xr = (m >= 0) ? (x + (size_t)m * 16) : zrow;
        const float* wk = Wt + (size_t)k * 16 * 32;
        f4 w0 = *(const f4*)(wk + (0 * 32 + co) * 4);
        f4 w1 = *(const f4*)(wk + (1 * 32 + co) * 4);
        f4 w2 = *(const f4*)(wk + (2 * 32 + co) * 4);
        f4 w3 = *(const f4*)(wk + (3 * 32 + co) * 4);
        f4 x0 = *(const f4*)(xr);
        f4 x1 = *(const f4*)(xr + 4);
        f4 x2 = *(const f4*)(xr + 8);
        f4 x3 = *(const f4*)(xr + 12);
        #pragma unroll
        for (int u = 0; u < 4; ++u) {
            a0 = fmaf(x0[u], w0[u], a0);
            a1 = fmaf(x1[u], w1[u], a1);
            a2 = fmaf(x2[u], w2[u], a2);
            a3 = fmaf(x3[u], w3[u], a3);
        }
    }
    if (j < N) out[(size_t)j * 32 + co] = (_Float16)((a0 + a1) + (a2 + a3));
}

// ---------------------------------------------------------------------------
// conv0t: concat(d1[*,64]h, s1[*,32]h) -> out[N0,2] fp32. ctz-union loop.
// ---------------------------------------------------------------------------
__global__ __launch_bounds__(256)
void sconv0t(const _Float16* __restrict__ d1, const _Float16* __restrict__ s1,
             const float* __restrict__ W /*[27,96,2]*/,
             const int* __restrict__ map, int N, float* __restrict__ out,
             const _Float16* __restrict__ zrh)
{
    const int tid  = threadIdx.x;
    const int lane = tid & 63;
    const int l32  = tid & 31;
    const int j    = blockIdx.x * 8 + (tid >> 5);

    int mk = (l32 < 27 && j < N) ? map[(size_t)l32 * N + j] : -1;
    const unsigned long long bal = __ballot(mk >= 0);
    unsigned int act = (unsigned int)((bal | (bal >> 32)) & 0x7FFFFFFu);

    float a0 = 0.f, a1 = 0.f;
    while (act) {
        const int k = (int)__builtin_ctz(act);
        act &= act - 1;
        const int m = __shfl(mk, (lane & 32) + k);
        const _Float16* p1 = (m >= 0) ? (d1 + (size_t)m * 64) : zrh;
        const _Float16* p2 = (m >= 0) ? (s1 + (size_t)m * 32) : zrh;
        const float* w = W + (size_t)k * 96 * 2;
        const float x0 = (float)p1[l32];
        const float x1 = (float)p1[l32 + 32];
        const float x2 = (float)p2[l32];
        a0 = fmaf(x0, w[l32 * 2 + 0], a0);
        a1 = fmaf(x0, w[l32 * 2 + 1], a1);
        a0 = fmaf(x1, w[(l32 + 32) * 2 + 0], a0);
        a1 = fmaf(x1, w[(l32 + 32) * 2 + 1], a1);
        a0 = fmaf(x2, w[(l32 + 64) * 2 + 0], a0);
        a1 = fmaf(x2, w[(l32 + 64) * 2 + 1], a1);
    }
    #pragma unroll
    for (int off = 1; off < 32; off <<= 1) {
        a0 += __shfl_xor(a0, off, 32);
        a1 += __shfl_xor(a1, off, 32);
    }
    if (l32 == 0 && j < N) {
        out[(size_t)j * 2 + 0] = a0;
        out[(size_t)j * 2 + 1] = a1;
    }
}

// ---------------------------------------------------------------------------
// BN pass 1 on half tensors
// ---------------------------------------------------------------------------
template<int C>
__global__ __launch_bounds__(256)
void bn_reduce_h(const _Float16* __restrict__ x, int N,
                 float* __restrict__ sums)
{
    constexpr int RG = 256 / C;
    const int tid = threadIdx.x;
    const int c   = tid % C;
    const int rg  = tid / C;
    float s = 0.f, s2 = 0.f;
    for (int j = blockIdx.x * RG + rg; j < N; j += gridDim.x * RG) {
        const float v = (float)x[(size_t)j * C + c];
        s += v;
        s2 += v * v;
    }
    __shared__ float sh[2 * 256];
    sh[tid] = s;
    sh[256 + tid] = s2;
    __syncthreads();
    for (int stride = 128; stride >= C; stride >>= 1) {
        if (tid < stride) {
            sh[tid] += sh[tid + stride];
            sh[256 + tid] += sh[256 + tid + stride];
        }
        __syncthreads();
    }
    if (tid < C) {
        atomicAdd(&sums[c], sh[tid]);
        atomicAdd(&sums[C + c], sh[256 + tid]);
    }
}

// ---------------------------------------------------------------------------
// BN pass 2 on half tensors
// ---------------------------------------------------------------------------
template<int C>
__global__ __launch_bounds__(256)
void bn_apply_h(_Float16* __restrict__ x, int N,
                const float* __restrict__ sums,
                const float* __restrict__ g, const float* __restrict__ b)
{
    const int tid = blockIdx.x * blockDim.x + threadIdx.x;
    const int c = tid % C;
    const float invN = 1.0f / (float)N;
    const float mean = sums[c] * invN;
    float var = sums[C + c] * invN - mean * mean;
    var = fmaxf(var, 0.f);
    const float sc = g[c] * rsqrtf(var + BN_EPS);
    const float sh = b[c] - mean * sc;
    const int rows_stride = (gridDim.x * blockDim.x) / C;
    for (int j = tid / C; j < N; j += rows_stride) {
        const size_t i = (size_t)j * C + c;
        const float v = fmaf((float)x[i], sc, sh);
        x[i] = (_Float16)(v > 0.f ? v : 0.f);
    }
}

// ---------------------------------------------------------------------------
extern "C" void kernel_launch(void* const* d_in, const int* in_sizes, int n_in,
                              void* d_out, int out_size, void* d_ws, size_t ws_size,
                              hipStream_t stream)
{
    const float* feats = (const float*)d_in[0];
    const float* W0  = (const float*)d_in[1];
    const float* g0  = (const float*)d_in[2];
    const float* b0  = (const float*)d_in[3];
    const float* W1  = (const float*)d_in[4];
    const float* g1  = (const float*)d_in[5];
    const float* b1  = (const float*)d_in[6];
    const float* W2  = (const float*)d_in[7];
    const float* g2  = (const float*)d_in[8];
    const float* b2  = (const float*)d_in[9];
    const float* W2t = (const float*)d_in[10];
    const float* g2t = (const float*)d_in[11];
    const float* b2t = (const float*)d_in[12];
    const float* W1t = (const float*)d_in[13];
    const float* g1t = (const float*)d_in[14];
    const float* b1t = (const float*)d_in[15];
    const float* W0t = (const float*)d_in[16];
    const int* map0  = (const int*)d_in[17];
    const int* map1  = (const int*)d_in[18];
    const int* map2  = (const int*)d_in[19];
    const int* map2t = (const int*)d_in[20];
    const int* map1t = (const int*)d_in[21];
    const int* map0t = (const int*)d_in[22];

    const int N0 = in_sizes[0] / 16;
    const int N1 = in_sizes[18] / 27;
    const int N2 = in_sizes[19] / 27;

    const int Npad0 = (N0 + 15) & ~15;
    const int Npad1 = (N1 + 15) & ~15;

    float* ws = (float*)d_ws;
    float* sums  = ws;          // 704 floats of BN accumulators
    float* sums0 = sums;        // 2*32
    float* sums1 = sums + 64;   // 2*64
    float* sums2 = sums + 192;  // 2*128
    float* sums3 = sums + 448;  // 2*64
    float* sums4 = sums + 576;  // 2*64
    float* zrow  = sums + 704;  // 128 zeroed floats (fp32 & f16 zero rows)
    int*   gcnt  = (int*)(zrow + 128);  // 64 ints: 2x gcursor[9] regions
    float* Wt0   = (float*)(gcnt + 64); // 27*16*32 fp32
    _Float16* hb = (_Float16*)(Wt0 + 27 * 16 * 32);
    _Float16* Wh1  = hb;                        // 27*32*64
    _Float16* Wh2  = Wh1 + 27 * 32 * 64;        // 27*64*128  (MFMA layout)
    _Float16* Wh2t = Wh2 + 27 * 64 * 128;       // 27*128*64  (MFMA layout)
    _Float16* Wh1t = Wh2t + 27 * 128 * 64;      // 27*128*64  (MFMA layout)
    _Float16* y0 = Wh1t + 27 * 128 * 64;        // [N0,32]  s1
    _Float16* y1 = y0 + (size_t)N0 * 32;        // [N1,64]  s2
    _Float16* y2 = y1 + (size_t)N1 * 64;        // [N2,128] s4
    _Float16* y3 = y2 + (size_t)N2 * 128;       // [N1,64]  d2
    _Float16* y4 = y3 + (size_t)N1 * 64;        // [N0,64]  d1
    int* mapT = (int*)(y4 + (size_t)N0 * 64);   // [Nmax,32] transposed map
    int* orderA = mapT + (size_t)N0 * 32;       // [9*Npad1] block2_tr groups
    int* orderB = orderA + (size_t)9 * Npad1;   // [9*Npad0] block1_tr groups
    const _Float16* zrh = (const _Float16*)zrow;

    (void)hipMemsetAsync(sums, 0, (704 + 128 + 64) * sizeof(float), stream);
    (void)hipMemsetAsync(orderA, 0xFF,
                         (size_t)9 * (Npad1 + Npad0) * sizeof(int), stream);

    // weight transposes (tiny)
    wtrans<16, 32><<<(27 * 4 * 32 + 255) / 256, 256, 0, stream>>>(W0, Wt0);
    wtrans_h<32, 64><<<(27 * 4 * 64 + 255) / 256, 256, 0, stream>>>(W1, Wh1);
    wtrans_mf<64, 128><<<(27 * 2 * 8 * 64 + 255) / 256, 256, 0, stream>>>(W2, Wh2);
    wtrans_mf<128, 64><<<(27 * 4 * 4 * 64 + 255) / 256, 256, 0, stream>>>(W2t, Wh2t);
    wtrans_mf<128, 64><<<(27 * 4 * 4 * 64 + 255) / 256, 256, 0, stream>>>(W1t, Wh1t);

    // block0: feats[N0,16] fp32 -> y0[N0,32] half
    sconv0<<<(N0 + 7) / 8, 256, 0, stream>>>(feats, Wt0, map0, N0, y0, zrow);
    bn_reduce_h<32><<<256, 256, 0, stream>>>(y0, N0, sums0);
    bn_apply_h<32><<<512, 256, 0, stream>>>(y0, N0, sums0, g0, b0);

    // block1 (SPARSE map): one wave per row (scalar dot2 path)
    map_transpose<<<(N1 + 255) / 256, 256, 0, stream>>>(map1, N1, mapT);
    sconv_r1<32, 32, 64><<<(N1 + 3) / 4, 256, 0, stream>>>(
        y0, nullptr, Wh1, mapT, N1, y1);
    bn_reduce_h<64><<<256, 256, 0, stream>>>(y1, N1, sums1);
    bn_apply_h<64><<<512, 256, 0, stream>>>(y1, N1, sums1, g1, b1);

    // block2: MFMA ungrouped (map2 not parity-gated)
    sconv_mf<64, 64, 128><<<(N2 + 63) / 64, 256, 0, stream>>>(
        y1, nullptr, Wh2, map2, N2, y2, zrh);
    bn_reduce_h<128><<<256, 256, 0, stream>>>(y2, N2, sums2);
    bn_apply_h<128><<<512, 256, 0, stream>>>(y2, N2, sums2, g2, b2);

    // block2_tr: parity-grouped MFMA (k-union <=8 per wave)
    map_transpose_grp<<<(N1 + 255) / 256, 256, 0, stream>>>(
        map2t, N1, Npad1, mapT, gcnt, orderA);
    sconv_mf_g<128, 128, 64><<<(9 * Npad1 + 63) / 64, 256, 0, stream>>>(
        y2, nullptr, Wh2t, mapT, orderA, 9 * Npad1, N1, y3, zrh);
    bn_reduce_h<64><<<256, 256, 0, stream>>>(y3, N1, sums3);
    bn_apply_h<64><<<512, 256, 0, stream>>>(y3, N1, sums3, g2t, b2t);

    // block1_tr: parity-grouped MFMA, concat input (y3[64] ++ y1[64])
    map_transpose_grp<<<(N0 + 255) / 256, 256, 0, stream>>>(
        map1t, N0, Npad0, mapT, gcnt + 32, orderB);
    sconv_mf_g<128, 64, 64><<<(9 * Npad0 + 63) / 64, 256, 0, stream>>>(
        y3, y1, Wh1t, mapT, orderB, 9 * Npad0, N0, y4, zrh);
    bn_reduce_h<64><<<256, 256, 0, stream>>>(y4, N0, sums4);
    bn_apply_h<64><<<512, 256, 0, stream>>>(y4, N0, sums4, g1t, b1t);

    // block0_tr: concat(d1,s1)[N0,96] -> out[N0,2] fp32
    sconv0t<<<(N0 + 7) / 8, 256, 0, stream>>>(y4, y0, W0t, map0t, N0,
                                              (float*)d_out, zrh);
}

// Round 7
// 859.900 us; speedup vs baseline: 5.8245x; 1.0848x over previous
//
#include <hip/hip_runtime.h>
#include <cstddef>
#include <cstdint>

#define BN_EPS 1e-5f

typedef float f4 __attribute__((ext_vector_type(4)));
typedef float f32x4 __attribute__((ext_vector_type(4)));
typedef _Float16 h2 __attribute__((ext_vector_type(2)));
typedef _Float16 h8 __attribute__((ext_vector_type(8)));

#if defined(__has_builtin)
#if __has_builtin(__builtin_amdgcn_fdot2)
#define DOT2(a, b, c) __builtin_amdgcn_fdot2((a), (b), (c), false)
#endif
#endif
#ifndef DOT2
#define DOT2(a, b, c) fmaf((float)(a)[1], (float)(b)[1], fmaf((float)(a)[0], (float)(b)[0], (c)))
#endif

// ---------------------------------------------------------------------------
// f16 weight transpose (sconv_r1): W[27][CIN][COUT] -> Wh[k][ci/8][co][8]
// ---------------------------------------------------------------------------
template<int CIN, int COUT>
__global__ __launch_bounds__(256)
void wtrans_h(const float* __restrict__ W, _Float16* __restrict__ Wh)
{
    const int t = blockIdx.x * 256 + threadIdx.x;
    constexpr int TOTAL = 27 * (CIN / 8) * COUT;
    if (t >= TOTAL) return;
    const int co = t % COUT;
    const int rest = t / COUT;
    const int t8 = rest % (CIN / 8);
    const int k  = rest / (CIN / 8);
    h8 v;
    #pragma unroll
    for (int u = 0; u < 8; ++u)
        v[u] = (_Float16)W[((size_t)k * CIN + t8 * 8 + u) * COUT + co];
    *(h8*)(Wh + (size_t)t * 8) = v;
}

// ---------------------------------------------------------------------------
// MFMA weight transform: W[27][CIN][COUT] fp32 -> B-fragment layout f16:
// Wm[((k*NT + t)*NC + ct)*64 + lane][8], h8 holds B[kk][co] with
// kk = t*32 + (lane>>4)*8 + u, co = ct*16 + (lane&15).
// ---------------------------------------------------------------------------
template<int CIN, int COUT>
__global__ __launch_bounds__(256)
void wtrans_mf(const float* __restrict__ W, _Float16* __restrict__ Wm)
{
    constexpr int NT = CIN / 32;
    constexpr int NC = COUT / 16;
    const int t = blockIdx.x * 256 + threadIdx.x;
    constexpr int TOTAL = 27 * NT * NC * 64;
    if (t >= TOTAL) return;
    const int lane = t & 63;
    int rest = t >> 6;
    const int ct = rest % NC; rest /= NC;
    const int tt = rest % NT;
    const int k  = rest / NT;
    const int cin0 = tt * 32 + (lane >> 4) * 8;
    const int co   = ct * 16 + (lane & 15);
    h8 v;
    #pragma unroll
    for (int u = 0; u < 8; ++u)
        v[u] = (_Float16)W[((size_t)k * CIN + cin0 + u) * COUT + co];
    *(h8*)(Wm + (size_t)t * 8) = v;
}

// ---------------------------------------------------------------------------
// conv0 MFMA weight transform (CIN=16, COUT=32, k-PAIRED):
// Wm0[((k*2 + s)*32 + co)*8 + u] = f16(W0[k][s*8+u][co]).
// A lane with (kseg,col) for pair (k1,k2) loads from (ksel, s=kseg&1, co).
// ---------------------------------------------------------------------------
__global__ __launch_bounds__(256)
void wtrans_mf0(const float* __restrict__ W, _Float16* __restrict__ Wm0)
{
    const int t = blockIdx.x * 256 + threadIdx.x;
    constexpr int TOTAL = 27 * 2 * 32;
    if (t >= TOTAL) return;
    const int co = t % 32;
    const int s  = (t / 32) % 2;
    const int k  = t / 64;
    h8 v;
    #pragma unroll
    for (int u = 0; u < 8; ++u)
        v[u] = (_Float16)W[((size_t)k * 16 + s * 8 + u) * 32 + co];
    *(h8*)(Wm0 + (size_t)t * 8) = v;
}

// ---------------------------------------------------------------------------
// Map transpose: map[27][Nout] -> mapT[Nout][32] (k-major per row, -1 pad).
// ---------------------------------------------------------------------------
__global__ __launch_bounds__(256)
void map_transpose(const int* __restrict__ map, int Nout,
                   int* __restrict__ mapT)
{
    __shared__ int s[256][28];
    const int tid  = threadIdx.x;
    const int base = blockIdx.x * 256;
    const int j    = base + tid;
    for (int k = 0; k < 27; ++k)
        s[tid][k] = (j < Nout) ? map[(size_t)k * Nout + j] : -1;
    __syncthreads();
    for (int i = tid; i < 256 * 32; i += 256) {
        const int r = i >> 5, c = i & 31;
        if (base + r < Nout)
            mapT[(size_t)(base + r) * 32 + c] = (c < 27) ? s[r][c] : -1;
    }
}

// ---------------------------------------------------------------------------
// Map transpose + parity-class GROUPING, contention-free: LDS histogram ->
// 9 global atomics PER BLOCK -> LDS cursors. Class regions fixed at c*Npad
// in order[] (unfilled slots stay -1, pre-memset 0xFF). Perf heuristic only.
// ---------------------------------------------------------------------------
__global__ __launch_bounds__(256)
void map_transpose_grp(const int* __restrict__ map, int Nout, int Npad,
                       int* __restrict__ mapT, int* __restrict__ gcursor,
                       int* __restrict__ order)
{
    __shared__ int s[256][28];
    __shared__ int hist[9], basec[9], cur[9];
    const int tid  = threadIdx.x;
    const int base = blockIdx.x * 256;
    const int j    = base + tid;
    if (tid < 9) { hist[tid] = 0; cur[tid] = 0; }
    for (int k = 0; k < 27; ++k)
        s[tid][k] = (j < Nout) ? map[(size_t)k * Nout + j] : -1;
    __syncthreads();
    for (int i = tid; i < 256 * 32; i += 256) {
        const int r = i >> 5, c = i & 31;
        if (base + r < Nout)
            mapT[(size_t)(base + r) * 32 + c] = (c < 27) ? s[r][c] : -1;
    }
    int c9 = 8;
    if (j < Nout) {
        #pragma unroll 1
        for (int k = 0; k < 27; ++k) {
            if (s[tid][k] >= 0) {
                const int dz = k % 3, dy = (k / 3) % 3, dx = k / 9;
                c9 = ((dx != 1) << 2) | ((dy != 1) << 1) | (int)(dz != 1);
                break;
            }
        }
        atomicAdd(&hist[c9], 1);
    }
    __syncthreads();
    if (tid < 9 && hist[tid] > 0)
        basec[tid] = atomicAdd(&gcursor[tid], hist[tid]);
    __syncthreads();
    if (j < Nout) {
        const int lpos = atomicAdd(&cur[c9], 1);
        order[(size_t)c9 * Npad + basec[c9] + lpos] = j;
    }
}

// ---------------------------------------------------------------------------
// R=1 f16 sparse conv (SPARSE maps): one wave = one row. (block1)
// ---------------------------------------------------------------------------
template<int CIN, int CINA, int COUT>
__global__ __launch_bounds__(256)
void sconv_r1(const _Float16* __restrict__ xA, const _Float16* __restrict__ xB,
              const _Float16* __restrict__ Wh, const int* __restrict__ mapT,
              int Nout, _Float16* __restrict__ out)
{
    constexpr int CINB = CIN - CINA;
    constexpr int CPL  = COUT / 64;
    constexpr int NT   = CIN / 8;
    const int lane = threadIdx.x & 63;
    const int j    = blockIdx.x * 4 + (threadIdx.x >> 6);

    int mk = -1;
    if (j < Nout && lane < 32) mk = mapT[(size_t)j * 32 + lane];
    unsigned long long act = __ballot(mk >= 0);   // bits 0..26 only

    float acc[CPL];
    #pragma unroll
    for (int c = 0; c < CPL; ++c) acc[c] = 0.f;

    while (act) {
        const int k = (int)__builtin_ctzll(act);
        act &= act - 1;
        const int m = __builtin_amdgcn_readlane(mk, k);   // uniform SGPR

        const _Float16* pA = xA + (size_t)m * CINA;
        const _Float16* pB = nullptr;
        if constexpr (CINB > 0) pB = xB + (size_t)m * CINB;

        const _Float16* Wk = Wh + (size_t)k * NT * COUT * 8;

        #pragma unroll
        for (int t = 0; t < NT; ++t) {
            const int ci = t * 8;
            h8 wv[CPL];
            #pragma unroll
            for (int c = 0; c < CPL; ++c)
                wv[c] = *(const h8*)(Wk + ((size_t)t * COUT + c * 64 + lane) * 8);
            const _Float16* p;
            if constexpr (CINB > 0)
                p = (ci < CINA) ? (pA + ci) : (pB + (ci - CINA));
            else
                p = pA + ci;
            const h8 xv = *(const h8*)p;
            const h2* xp = (const h2*)&xv;
            #pragma unroll
            for (int q = 0; q < 4; ++q) {
                #pragma unroll
                for (int c = 0; c < CPL; ++c) {
                    const h2* wp = (const h2*)&wv[c];
                    acc[c] = DOT2(xp[q], wp[q], acc[c]);
                }
            }
        }
    }

    if (j < Nout) {
        #pragma unroll
        for (int c = 0; c < CPL; ++c)
            out[(size_t)j * COUT + c * 64 + lane] = (_Float16)acc[c];
    }
}

// ---------------------------------------------------------------------------
// conv0 MFMA (CIN=16 fp32 in, COUT=32, k-PAIRED, compensated hi/lo):
// one wave = 16 rows. Two active offsets share one K=32 MFMA step (kseg 0/1
// lanes carry k1's cin 0..15, kseg 2/3 carry k2's). fp32 x is split
// x = hi + lo/2048 (hi=f16(x), lo=f16((x-hi)*2048)); two accumulator chains,
// D = accH + accL/2048 -- exact in x, error only from f16(W0) (~2^-11 rel),
// matching the existing f16 y0 cast error. A and B use the same
// slot->(offset,cin) mapping so the HW k-permutation cancels.
// ---------------------------------------------------------------------------
__global__ __launch_bounds__(256)
void sconv_mf0(const float* __restrict__ x, const _Float16* __restrict__ Wm0,
               const int* __restrict__ map, int Nout,
               _Float16* __restrict__ out, const float* __restrict__ zrow)
{
    const int lane = threadIdx.x & 63;
    const int wave = threadIdx.x >> 6;
    const int row0 = (blockIdx.x * 4 + wave) * 16;

    __shared__ int smap[4][16][28];

    int mk[16];
    bool anyv = false;
    #pragma unroll
    for (int r = 0; r < 16; ++r) {
        const int j = row0 + r;
        mk[r] = (lane < 27 && j < Nout) ? map[(size_t)lane * Nout + j] : -1;
        anyv |= (mk[r] >= 0);
    }
    unsigned long long act = __ballot(anyv);

    if (lane < 27) {
        #pragma unroll
        for (int r = 0; r < 16; ++r)
            smap[wave][r][lane] = mk[r];
    }

    f32x4 accH[2], accL[2];
    #pragma unroll
    for (int c = 0; c < 2; ++c) {
        accH[c] = (f32x4){0.f, 0.f, 0.f, 0.f};
        accL[c] = (f32x4){0.f, 0.f, 0.f, 0.f};
    }

    const int rrow = lane & 15;   // A row / D col
    const int kseg = lane >> 4;
    const int half = kseg & 1;    // cin half: 0 -> 0..7, 1 -> 8..15
    const bool useK1 = (kseg < 2);

    while (act) {
        const int k1 = (int)__builtin_ctzll(act);
        act &= act - 1;
        int k2 = -1;
        if (act) {
            k2 = (int)__builtin_ctzll(act);
            act &= act - 1;
        }
        const int ks = useK1 ? k1 : k2;
        int m = -1;
        if (ks >= 0) m = smap[wave][rrow][ks];

        const float* px = (m >= 0) ? (x + (size_t)m * 16 + half * 8)
                                   : (zrow + half * 8);
        const f4 x0 = *(const f4*)px;
        const f4 x1 = *(const f4*)(px + 4);
        h8 aH, aL;
        #pragma unroll
        for (int u = 0; u < 4; ++u) {
            const float v0 = x0[u], v1 = x1[u];
            const _Float16 h0 = (_Float16)v0;
            const _Float16 h1 = (_Float16)v1;
            aH[u]     = h0;
            aH[u + 4] = h1;
            aL[u]     = (_Float16)((v0 - (float)h0) * 2048.f);
            aL[u + 4] = (_Float16)((v1 - (float)h1) * 2048.f);
        }

        const int ksafe = (ks >= 0) ? ks : 0;   // a==0 makes b irrelevant
        const _Float16* wb = Wm0 + ((size_t)(ksafe * 2 + half) * 32) * 8;
        #pragma unroll
        for (int c = 0; c < 2; ++c) {
            const h8 b = *(const h8*)(wb + (size_t)(c * 16 + rrow) * 8);
            accH[c] = __builtin_amdgcn_mfma_f32_16x16x32_f16(aH, b, accH[c], 0, 0, 0);
            accL[c] = __builtin_amdgcn_mfma_f32_16x16x32_f16(aL, b, accL[c], 0, 0, 0);
        }
    }

    // D: lane (kseg,rrow), reg r -> row = kseg*4 + r, col = rrow
    #pragma unroll
    for (int c = 0; c < 2; ++c) {
        #pragma unroll
        for (int r = 0; r < 4; ++r) {
            const int j = row0 + kseg * 4 + r;
            if (j < Nout)
                out[(size_t)j * 32 + c * 16 + rrow] =
                    (_Float16)(accH[c][r] + accL[c][r] * (1.f / 2048.f));
        }
    }
}

// ---------------------------------------------------------------------------
// MFMA sparse conv (UNGROUPED, raw map): one wave = 16 consecutive rows.
// Used for block2 (non-parity-gated map). LDS-staged map + 1-deep pipeline.
// ---------------------------------------------------------------------------
template<int CIN, int CINA, int COUT>
__global__ __launch_bounds__(256)
void sconv_mf(const _Float16* __restrict__ xA, const _Float16* __restrict__ xB,
              const _Float16* __restrict__ Wm, const int* __restrict__ map,
              int Nout, _Float16* __restrict__ out,
              const _Float16* __restrict__ zrh)
{
    constexpr int CINB = CIN - CINA;
    constexpr int NT = CIN / 32;
    constexpr int NC = COUT / 16;
    static_assert(CINA % 32 == 0, "CINA must be a multiple of 32");
    const int lane = threadIdx.x & 63;
    const int wave = threadIdx.x >> 6;
    const int row0 = (blockIdx.x * 4 + wave) * 16;

    __shared__ int smap[4][16][28];

    int mk[16];
    bool anyv = false;
    #pragma unroll
    for (int r = 0; r < 16; ++r) {
        const int j = row0 + r;
        mk[r] = (lane < 27 && j < Nout) ? map[(size_t)lane * Nout + j] : -1;
        anyv |= (mk[r] >= 0);
    }
    unsigned long long act = __ballot(anyv);

    if (lane < 27) {
        #pragma unroll
        for (int r = 0; r < 16; ++r)
            smap[wave][r][lane] = mk[r];
    }

    f32x4 acc[NC];
    #pragma unroll
    for (int c = 0; c < NC; ++c) acc[c] = (f32x4){0.f, 0.f, 0.f, 0.f};

    const int rrow = lane & 15;
    const int kseg = lane >> 4;

    auto loada = [&](int k, h8* a) {
        const int m = smap[wave][rrow][k];
        #pragma unroll
        for (int t = 0; t < NT; ++t) {
            const int cin0 = t * 32 + kseg * 8;
            const _Float16* pa;
            if (m >= 0) {
                if (CINB > 0 && t * 32 >= CINA)
                    pa = xB + (size_t)m * CINB + (cin0 - CINA);
                else
                    pa = xA + (size_t)m * CINA + cin0;
            } else {
                pa = zrh;
            }
            a[t] = *(const h8*)pa;
        }
    };
    auto compute = [&](int k, const h8* a) {
        const _Float16* Wk = Wm + ((size_t)k * NT * NC * 64 + lane) * 8;
        #pragma unroll
        for (int t = 0; t < NT; ++t) {
            #pragma unroll
            for (int c = 0; c < NC; ++c) {
                const h8 b = *(const h8*)(Wk + (size_t)(t * NC + c) * 64 * 8);
                acc[c] = __builtin_amdgcn_mfma_f32_16x16x32_f16(a[t], b, acc[c], 0, 0, 0);
            }
        }
    };

    h8 aC[NT], aN[NT];
    int kC = -1;
    if (act) {
        kC = (int)__builtin_ctzll(act);
        act &= act - 1;
        loada(kC, aC);
    }
    while (kC >= 0) {
        int kN = -1;
        if (act) {
            kN = (int)__builtin_ctzll(act);
            act &= act - 1;
            loada(kN, aN);
        }
        compute(kC, aC);
        #pragma unroll
        for (int t = 0; t < NT; ++t) aC[t] = aN[t];
        kC = kN;
    }

    #pragma unroll
    for (int c = 0; c < NC; ++c) {
        #pragma unroll
        for (int r = 0; r < 4; ++r) {
            const int j = row0 + kseg * 4 + r;
            if (j < Nout)
                out[(size_t)j * COUT + c * 16 + rrow] = (_Float16)acc[c][r];
        }
    }
}

// ---------------------------------------------------------------------------
// MFMA sparse conv (GROUPED): wave's 16 rows come from order[] (same parity
// class -> k-union <= 8 vs <= 27). Slots with -1 skipped; dead waves exit
// after the ballot. 1-deep pipelined gathers.
// ---------------------------------------------------------------------------
template<int CIN, int CINA, int COUT>
__global__ __launch_bounds__(256)
void sconv_mf_g(const _Float16* __restrict__ xA, const _Float16* __restrict__ xB,
                const _Float16* __restrict__ Wm, const int* __restrict__ mapT,
                const int* __restrict__ order, int NTOT, int Nout,
                _Float16* __restrict__ out, const _Float16* __restrict__ zrh)
{
    constexpr int CINB = CIN - CINA;
    constexpr int NT = CIN / 32;
    constexpr int NC = COUT / 16;
    static_assert(CINA % 32 == 0, "CINA must be a multiple of 32");
    const int lane = threadIdx.x & 63;
    const int wave = threadIdx.x >> 6;
    const int wrow0 = (blockIdx.x * 4 + wave) * 16;

    __shared__ int sjr[4][16];
    __shared__ int smap[4][16][28];

    if (lane < 16) {
        const int idx = wrow0 + lane;
        sjr[wave][lane] = (idx < NTOT) ? order[idx] : -1;
    }
    const int kk = lane & 31;
    bool anyv = false;
    #pragma unroll
    for (int r = 0; r < 16; ++r) {
        const int jr = sjr[wave][r];
        int v = -1;
        if (jr >= 0 && kk < 27) v = mapT[(size_t)jr * 32 + kk];
        if (lane < 28) smap[wave][r][lane] = v;
        anyv |= (v >= 0);
    }
    const unsigned long long bal = __ballot(anyv);
    unsigned long long act = (bal | (bal >> 32)) & 0x7FFFFFFull;

    f32x4 acc[NC];
    #pragma unroll
    for (int c = 0; c < NC; ++c) acc[c] = (f32x4){0.f, 0.f, 0.f, 0.f};

    const int rrow = lane & 15;
    const int kseg = lane >> 4;

    auto loada = [&](int k, h8* a) {
        const int m = smap[wave][rrow][k];
        #pragma unroll
        for (int t = 0; t < NT; ++t) {
            const int cin0 = t * 32 + kseg * 8;
            const _Float16* pa;
            if (m >= 0) {
                if (CINB > 0 && t * 32 >= CINA)
                    pa = xB + (size_t)m * CINB + (cin0 - CINA);
                else
                    pa = xA + (size_t)m * CINA + cin0;
            } else {
                pa = zrh;
            }
            a[t] = *(const h8*)pa;
        }
    };
    auto compute = [&](int k, const h8* a) {
        const _Float16* Wk = Wm + ((size_t)k * NT * NC * 64 + lane) * 8;
        #pragma unroll
        for (int t = 0; t < NT; ++t) {
            #pragma unroll
            for (int c = 0; c < NC; ++c) {
                const h8 b = *(const h8*)(Wk + (size_t)(t * NC + c) * 64 * 8);
                acc[c] = __builtin_amdgcn_mfma_f32_16x16x32_f16(a[t], b, acc[c], 0, 0, 0);
            }
        }
    };

    h8 aC[NT], aN[NT];
    int kC = -1;
    if (act) {
        kC = (int)__builtin_ctzll(act);
        act &= act - 1;
        loada(kC, aC);
    }
    while (kC >= 0) {
        int kN = -1;
        if (act) {
            kN = (int)__builtin_ctzll(act);
            act &= act - 1;
            loada(kN, aN);
        }
        compute(kC, aC);
        #pragma unroll
        for (int t = 0; t < NT; ++t) aC[t] = aN[t];
        kC = kN;
    }

    #pragma unroll
    for (int c = 0; c < NC; ++c) {
        #pragma unroll
        for (int r = 0; r < 4; ++r) {
            const int j = sjr[wave][kseg * 4 + r];
            if (j >= 0)
                out[(size_t)j * COUT + c * 16 + rrow] = (_Float16)acc[c][r];
        }
    }
}

// ---------------------------------------------------------------------------
// conv0t: concat(d1[*,64]h, s1[*,32]h) -> out[N0,2] fp32. ctz-union loop.
// ---------------------------------------------------------------------------
__global__ __launch_bounds__(256)
void sconv0t(const _Float16* __restrict__ d1, const _Float16* __restrict__ s1,
             const float* __restrict__ W /*[27,96,2]*/,
             const int* __restrict__ map, int N, float* __restrict__ out,
             const _Float16* __restrict__ zrh)
{
    const int tid  = threadIdx.x;
    const int lane = tid & 63;
    const int l32  = tid & 31;
    const int j    = blockIdx.x * 8 + (tid >> 5);

    int mk = (l32 < 27 && j < N) ? map[(size_t)l32 * N + j] : -1;
    const unsigned long long bal = __ballot(mk >= 0);
    unsigned int act = (unsigned int)((bal | (bal >> 32)) & 0x7FFFFFFu);

    float a0 = 0.f, a1 = 0.f;
    while (act) {
        const int k = (int)__builtin_ctz(act);
        act &= act - 1;
        const int m = __shfl(mk, (lane & 32) + k);
        const _Float16* p1 = (m >= 0) ? (d1 + (size_t)m * 64) : zrh;
        const _Float16* p2 = (m >= 0) ? (s1 + (size_t)m * 32) : zrh;
        const float* w = W + (size_t)k * 96 * 2;
        const float x0 = (float)p1[l32];
        const float x1 = (float)p1[l32 + 32];
        const float x2 = (float)p2[l32];
        a0 = fmaf(x0, w[l32 * 2 + 0], a0);
        a1 = fmaf(x0, w[l32 * 2 + 1], a1);
        a0 = fmaf(x1, w[(l32 + 32) * 2 + 0], a0);
        a1 = fmaf(x1, w[(l32 + 32) * 2 + 1], a1);
        a0 = fmaf(x2, w[(l32 + 64) * 2 + 0], a0);
        a1 = fmaf(x2, w[(l32 + 64) * 2 + 1], a1);
    }
    #pragma unroll
    for (int off = 1; off < 32; off <<= 1) {
        a0 += __shfl_xor(a0, off, 32);
        a1 += __shfl_xor(a1, off, 32);
    }
    if (l32 == 0 && j < N) {
        out[(size_t)j * 2 + 0] = a0;
        out[(size_t)j * 2 + 1] = a1;
    }
}

// ---------------------------------------------------------------------------
// BN pass 1 on half tensors
// ---------------------------------------------------------------------------
template<int C>
__global__ __launch_bounds__(256)
void bn_reduce_h(const _Float16* __restrict__ x, int N,
                 float* __restrict__ sums)
{
    constexpr int RG = 256 / C;
    const int tid = threadIdx.x;
    const int c   = tid % C;
    const int rg  = tid / C;
    float s = 0.f, s2 = 0.f;
    for (int j = blockIdx.x * RG + rg; j < N; j += gridDim.x * RG) {
        const float v = (float)x[(size_t)j * C + c];
        s += v;
        s2 += v * v;
    }
    __shared__ float sh[2 * 256];
    sh[tid] = s;
    sh[256 + tid] = s2;
    __syncthreads();
    for (int stride = 128; stride >= C; stride >>= 1) {
        if (tid < stride) {
            sh[tid] += sh[tid + stride];
            sh[256 + tid] += sh[256 + tid + stride];
        }
        __syncthreads();
    }
    if (tid < C) {
        atomicAdd(&sums[c], sh[tid]);
        atomicAdd(&sums[C + c], sh[256 + tid]);
    }
}

// ---------------------------------------------------------------------------
// BN pass 2 on half tensors
// ---------------------------------------------------------------------------
template<int C>
__global__ __launch_bounds__(256)
void bn_apply_h(_Float16* __restrict__ x, int N,
                const float* __restrict__ sums,
                const float* __restrict__ g, const float* __restrict__ b)
{
    const int tid = blockIdx.x * blockDim.x + threadIdx.x;
    const int c = tid % C;
    const float invN = 1.0f / (float)N;
    const float mean = sums[c] * invN;
    float var = sums[C + c] * invN - mean * mean;
    var = fmaxf(var, 0.f);
    const float sc = g[c] * rsqrtf(var + BN_EPS);
    const float sh = b[c] - mean * sc;
    const int rows_stride = (gridDim.x * blockDim.x) / C;
    for (int j = tid / C; j < N; j += rows_stride) {
        const size_t i = (size_t)j * C + c;
        const float v = fmaf((float)x[i], sc, sh);
        x[i] = (_Float16)(v > 0.f ? v : 0.f);
    }
}

// ---------------------------------------------------------------------------
extern "C" void kernel_launch(void* const* d_in, const int* in_sizes, int n_in,
                              void* d_out, int out_size, void* d_ws, size_t ws_size,
                              hipStream_t stream)
{
    const float* feats = (const float*)d_in[0];
    const float* W0  = (const float*)d_in[1];
    const float* g0  = (const float*)d_in[2];
    const float* b0  = (const float*)d_in[3];
    const float* W1  = (const float*)d_in[4];
    const float* g1  = (const float*)d_in[5];
    const float* b1  = (const float*)d_in[6];
    const float* W2  = (const float*)d_in[7];
    const float* g2  = (const float*)d_in[8];
    const float* b2  = (const float*)d_in[9];
    const float* W2t = (const float*)d_in[10];
    const float* g2t = (const float*)d_in[11];
    const float* b2t = (const float*)d_in[12];
    const float* W1t = (const float*)d_in[13];
    const float* g1t = (const float*)d_in[14];
    const float* b1t = (const float*)d_in[15];
    const float* W0t = (const float*)d_in[16];
    const int* map0  = (const int*)d_in[17];
    const int* map1  = (const int*)d_in[18];
    const int* map2  = (const int*)d_in[19];
    const int* map2t = (const int*)d_in[20];
    const int* map1t = (const int*)d_in[21];
    const int* map0t = (const int*)d_in[22];

    const int N0 = in_sizes[0] / 16;
    const int N1 = in_sizes[18] / 27;
    const int N2 = in_sizes[19] / 27;

    const int Npad0 = (N0 + 15) & ~15;
    const int Npad1 = (N1 + 15) & ~15;

    float* ws = (float*)d_ws;
    float* sums  = ws;          // 704 floats of BN accumulators
    float* sums0 = sums;        // 2*32
    float* sums1 = sums + 64;   // 2*64
    float* sums2 = sums + 192;  // 2*128
    float* sums3 = sums + 448;  // 2*64
    float* sums4 = sums + 576;  // 2*64
    float* zrow  = sums + 704;  // 128 zeroed floats (fp32 & f16 zero rows)
    int*   gcnt  = (int*)(zrow + 128);  // 64 ints: 2x gcursor[9] regions
    _Float16* Wm0h = (_Float16*)(gcnt + 64);    // 27*2*32*8 f16 (paired MFMA)
    _Float16* Wh1  = Wm0h + 27 * 2 * 32 * 8;    // 27*32*64  (r1 layout)
    _Float16* Wh2  = Wh1 + 27 * 32 * 64;        // 27*64*128  (MFMA layout)
    _Float16* Wh2t = Wh2 + 27 * 64 * 128;       // 27*128*64  (MFMA layout)
    _Float16* Wh1t = Wh2t + 27 * 128 * 64;      // 27*128*64  (MFMA layout)
    _Float16* y0 = Wh1t + 27 * 128 * 64;        // [N0,32]  s1
    _Float16* y1 = y0 + (size_t)N0 * 32;        // [N1,64]  s2
    _Float16* y2 = y1 + (size_t)N1 * 64;        // [N2,128] s4
    _Float16* y3 = y2 + (size_t)N2 * 128;       // [N1,64]  d2
    _Float16* y4 = y3 + (size_t)N1 * 64;        // [N0,64]  d1
    int* mapT = (int*)(y4 + (size_t)N0 * 64);   // [Nmax,32] transposed map
    int* orderA = mapT + (size_t)N0 * 32;       // [9*Npad1] block2_tr groups
    int* orderB = orderA + (size_t)9 * Npad1;   // [9*Npad0] block1_tr groups
    const _Float16* zrh = (const _Float16*)zrow;

    (void)hipMemsetAsync(sums, 0, (704 + 128 + 64) * sizeof(float), stream);
    (void)hipMemsetAsync(orderA, 0xFF,
                         (size_t)9 * (Npad1 + Npad0) * sizeof(int), stream);

    // weight transposes (tiny)
    wtrans_mf0<<<(27 * 2 * 32 + 255) / 256, 256, 0, stream>>>(W0, Wm0h);
    wtrans_h<32, 64><<<(27 * 4 * 64 + 255) / 256, 256, 0, stream>>>(W1, Wh1);
    wtrans_mf<64, 128><<<(27 * 2 * 8 * 64 + 255) / 256, 256, 0, stream>>>(W2, Wh2);
    wtrans_mf<128, 64><<<(27 * 4 * 4 * 64 + 255) / 256, 256, 0, stream>>>(W2t, Wh2t);
    wtrans_mf<128, 64><<<(27 * 4 * 4 * 64 + 255) / 256, 256, 0, stream>>>(W1t, Wh1t);

    // block0: feats[N0,16] fp32 -> y0[N0,32] half. MFMA k-paired hi/lo.
    sconv_mf0<<<(N0 + 63) / 64, 256, 0, stream>>>(
        feats, Wm0h, map0, N0, y0, zrow);
    bn_reduce_h<32><<<256, 256, 0, stream>>>(y0, N0, sums0);
    bn_apply_h<32><<<512, 256, 0, stream>>>(y0, N0, sums0, g0, b0);

    // block1 (SPARSE map, ~1.3 k/row): one wave per row (scalar dot2 path)
    map_transpose<<<(N1 + 255) / 256, 256, 0, stream>>>(map1, N1, mapT);
    sconv_r1<32, 32, 64><<<(N1 + 3) / 4, 256, 0, stream>>>(
        y0, nullptr, Wh1, mapT, N1, y1);
    bn_reduce_h<64><<<256, 256, 0, stream>>>(y1, N1, sums1);
    bn_apply_h<64><<<512, 256, 0, stream>>>(y1, N1, sums1, g1, b1);

    // block2: MFMA ungrouped (map2 not parity-gated)
    sconv_mf<64, 64, 128><<<(N2 + 63) / 64, 256, 0, stream>>>(
        y1, nullptr, Wh2, map2, N2, y2, zrh);
    bn_reduce_h<128><<<256, 256, 0, stream>>>(y2, N2, sums2);
    bn_apply_h<128><<<512, 256, 0, stream>>>(y2, N2, sums2, g2, b2);

    // block2_tr: parity-grouped MFMA (k-union <=8 per wave)
    map_transpose_grp<<<(N1 + 255) / 256, 256, 0, stream>>>(
        map2t, N1, Npad1, mapT, gcnt, orderA);
    sconv_mf_g<128, 128, 64><<<(9 * Npad1 + 63) / 64, 256, 0, stream>>>(
        y2, nullptr, Wh2t, mapT, orderA, 9 * Npad1, N1, y3, zrh);
    bn_reduce_h<64><<<256, 256, 0, stream>>>(y3, N1, sums3);
    bn_apply_h<64><<<512, 256, 0, stream>>>(y3, N1, sums3, g2t, b2t);

    // block1_tr: parity-grouped MFMA, concat input (y3[64] ++ y1[64])
    map_transpose_grp<<<(N0 + 255) / 256, 256, 0, stream>>>(
        map1t, N0, Npad0, mapT, gcnt + 32, orderB);
    sconv_mf_g<128, 64, 64><<<(9 * Npad0 + 63) / 64, 256, 0, stream>>>(
        y3, y1, Wh1t, mapT, orderB, 9 * Npad0, N0, y4, zrh);
    bn_reduce_h<64><<<256, 256, 0, stream>>>(y4, N0, sums4);
    bn_apply_h<64><<<512, 256, 0, stream>>>(y4, N0, sums4, g1t, b1t);

    // block0_tr: concat(d1,s1)[N0,96] -> out[N0,2] fp32
    sconv0t<<<(N0 + 7) / 8, 256, 0, stream>>>(y4, y0, W0t, map0t, N0,
                                              (float*)d_out, zrh);
}

// Round 8
// 840.762 us; speedup vs baseline: 5.9571x; 1.0228x over previous
//
#include <hip/hip_runtime.h>
#include <cstddef>
#include <cstdint>

#define BN_EPS 1e-5f

typedef float f4 __attribute__((ext_vector_type(4)));
typedef float f32x4 __attribute__((ext_vector_type(4)));
typedef _Float16 h2 __attribute__((ext_vector_type(2)));
typedef _Float16 h8 __attribute__((ext_vector_type(8)));

#if defined(__has_builtin)
#if __has_builtin(__builtin_amdgcn_fdot2)
#define DOT2(a, b, c) __builtin_amdgcn_fdot2((a), (b), (c), false)
#endif
#endif
#ifndef DOT2
#define DOT2(a, b, c) fmaf((float)(a)[1], (float)(b)[1], fmaf((float)(a)[0], (float)(b)[0], (c)))
#endif

// ---------------------------------------------------------------------------
// f16 weight transpose (sconv_r1): W[27][CIN][COUT] -> Wh[k][ci/8][co][8]
// ---------------------------------------------------------------------------
template<int CIN, int COUT>
__global__ __launch_bounds__(256)
void wtrans_h(const float* __restrict__ W, _Float16* __restrict__ Wh)
{
    const int t = blockIdx.x * 256 + threadIdx.x;
    constexpr int TOTAL = 27 * (CIN / 8) * COUT;
    if (t >= TOTAL) return;
    const int co = t % COUT;
    const int rest = t / COUT;
    const int t8 = rest % (CIN / 8);
    const int k  = rest / (CIN / 8);
    h8 v;
    #pragma unroll
    for (int u = 0; u < 8; ++u)
        v[u] = (_Float16)W[((size_t)k * CIN + t8 * 8 + u) * COUT + co];
    *(h8*)(Wh + (size_t)t * 8) = v;
}

// ---------------------------------------------------------------------------
// MFMA weight transform: W[27][CIN][COUT] fp32 -> B-fragment layout f16:
// Wm[((k*NT + t)*NC + ct)*64 + lane][8], h8 holds B[kk][co] with
// kk = t*32 + (lane>>4)*8 + u, co = ct*16 + (lane&15).
// ---------------------------------------------------------------------------
template<int CIN, int COUT>
__global__ __launch_bounds__(256)
void wtrans_mf(const float* __restrict__ W, _Float16* __restrict__ Wm)
{
    constexpr int NT = CIN / 32;
    constexpr int NC = COUT / 16;
    const int t = blockIdx.x * 256 + threadIdx.x;
    constexpr int TOTAL = 27 * NT * NC * 64;
    if (t >= TOTAL) return;
    const int lane = t & 63;
    int rest = t >> 6;
    const int ct = rest % NC; rest /= NC;
    const int tt = rest % NT;
    const int k  = rest / NT;
    const int cin0 = tt * 32 + (lane >> 4) * 8;
    const int co   = ct * 16 + (lane & 15);
    h8 v;
    #pragma unroll
    for (int u = 0; u < 8; ++u)
        v[u] = (_Float16)W[((size_t)k * CIN + cin0 + u) * COUT + co];
    *(h8*)(Wm + (size_t)t * 8) = v;
}

// ---------------------------------------------------------------------------
// conv0 MFMA weight transform (CIN=16, COUT=32, k-PAIRED):
// Wm0[((k*2 + s)*32 + co)*8 + u] = f16(W0[k][s*8+u][co]).
// ---------------------------------------------------------------------------
__global__ __launch_bounds__(256)
void wtrans_mf0(const float* __restrict__ W, _Float16* __restrict__ Wm0)
{
    const int t = blockIdx.x * 256 + threadIdx.x;
    constexpr int TOTAL = 27 * 2 * 32;
    if (t >= TOTAL) return;
    const int co = t % 32;
    const int s  = (t / 32) % 2;
    const int k  = t / 64;
    h8 v;
    #pragma unroll
    for (int u = 0; u < 8; ++u)
        v[u] = (_Float16)W[((size_t)k * 16 + s * 8 + u) * 32 + co];
    *(h8*)(Wm0 + (size_t)t * 8) = v;
}

// ---------------------------------------------------------------------------
// Map transpose: map[27][Nout] -> mapT[Nout][32] (k-major per row, -1 pad).
// ---------------------------------------------------------------------------
__global__ __launch_bounds__(256)
void map_transpose(const int* __restrict__ map, int Nout,
                   int* __restrict__ mapT)
{
    __shared__ int s[256][28];
    const int tid  = threadIdx.x;
    const int base = blockIdx.x * 256;
    const int j    = base + tid;
    for (int k = 0; k < 27; ++k)
        s[tid][k] = (j < Nout) ? map[(size_t)k * Nout + j] : -1;
    __syncthreads();
    for (int i = tid; i < 256 * 32; i += 256) {
        const int r = i >> 5, c = i & 31;
        if (base + r < Nout)
            mapT[(size_t)(base + r) * 32 + c] = (c < 27) ? s[r][c] : -1;
    }
}

// ---------------------------------------------------------------------------
// Map transpose + parity-class GROUPING, contention-free: LDS histogram ->
// 9 global atomics PER BLOCK -> LDS cursors. Class regions fixed at c*Npad
// in order[] (unfilled slots stay -1, pre-memset 0xFF). Perf heuristic only.
// ---------------------------------------------------------------------------
__global__ __launch_bounds__(256)
void map_transpose_grp(const int* __restrict__ map, int Nout, int Npad,
                       int* __restrict__ mapT, int* __restrict__ gcursor,
                       int* __restrict__ order)
{
    __shared__ int s[256][28];
    __shared__ int hist[9], basec[9], cur[9];
    const int tid  = threadIdx.x;
    const int base = blockIdx.x * 256;
    const int j    = base + tid;
    if (tid < 9) { hist[tid] = 0; cur[tid] = 0; }
    for (int k = 0; k < 27; ++k)
        s[tid][k] = (j < Nout) ? map[(size_t)k * Nout + j] : -1;
    __syncthreads();
    for (int i = tid; i < 256 * 32; i += 256) {
        const int r = i >> 5, c = i & 31;
        if (base + r < Nout)
            mapT[(size_t)(base + r) * 32 + c] = (c < 27) ? s[r][c] : -1;
    }
    int c9 = 8;
    if (j < Nout) {
        #pragma unroll 1
        for (int k = 0; k < 27; ++k) {
            if (s[tid][k] >= 0) {
                const int dz = k % 3, dy = (k / 3) % 3, dx = k / 9;
                c9 = ((dx != 1) << 2) | ((dy != 1) << 1) | (int)(dz != 1);
                break;
            }
        }
        atomicAdd(&hist[c9], 1);
    }
    __syncthreads();
    if (tid < 9 && hist[tid] > 0)
        basec[tid] = atomicAdd(&gcursor[tid], hist[tid]);
    __syncthreads();
    if (j < Nout) {
        const int lpos = atomicAdd(&cur[c9], 1);
        order[(size_t)c9 * Npad + basec[c9] + lpos] = j;
    }
}

// ---------------------------------------------------------------------------
// R=1 f16 sparse conv (SPARSE maps): one wave = one row. (block1)
// ---------------------------------------------------------------------------
template<int CIN, int CINA, int COUT>
__global__ __launch_bounds__(256)
void sconv_r1(const _Float16* __restrict__ xA, const _Float16* __restrict__ xB,
              const _Float16* __restrict__ Wh, const int* __restrict__ mapT,
              int Nout, _Float16* __restrict__ out)
{
    constexpr int CINB = CIN - CINA;
    constexpr int CPL  = COUT / 64;
    constexpr int NT   = CIN / 8;
    const int lane = threadIdx.x & 63;
    const int j    = blockIdx.x * 4 + (threadIdx.x >> 6);

    int mk = -1;
    if (j < Nout && lane < 32) mk = mapT[(size_t)j * 32 + lane];
    unsigned long long act = __ballot(mk >= 0);   // bits 0..26 only

    float acc[CPL];
    #pragma unroll
    for (int c = 0; c < CPL; ++c) acc[c] = 0.f;

    while (act) {
        const int k = (int)__builtin_ctzll(act);
        act &= act - 1;
        const int m = __builtin_amdgcn_readlane(mk, k);   // uniform SGPR

        const _Float16* pA = xA + (size_t)m * CINA;
        const _Float16* pB = nullptr;
        if constexpr (CINB > 0) pB = xB + (size_t)m * CINB;

        const _Float16* Wk = Wh + (size_t)k * NT * COUT * 8;

        #pragma unroll
        for (int t = 0; t < NT; ++t) {
            const int ci = t * 8;
            h8 wv[CPL];
            #pragma unroll
            for (int c = 0; c < CPL; ++c)
                wv[c] = *(const h8*)(Wk + ((size_t)t * COUT + c * 64 + lane) * 8);
            const _Float16* p;
            if constexpr (CINB > 0)
                p = (ci < CINA) ? (pA + ci) : (pB + (ci - CINA));
            else
                p = pA + ci;
            const h8 xv = *(const h8*)p;
            const h2* xp = (const h2*)&xv;
            #pragma unroll
            for (int q = 0; q < 4; ++q) {
                #pragma unroll
                for (int c = 0; c < CPL; ++c) {
                    const h2* wp = (const h2*)&wv[c];
                    acc[c] = DOT2(xp[q], wp[q], acc[c]);
                }
            }
        }
    }

    if (j < Nout) {
        #pragma unroll
        for (int c = 0; c < CPL; ++c)
            out[(size_t)j * COUT + c * 64 + lane] = (_Float16)acc[c];
    }
}

// ---------------------------------------------------------------------------
// conv0 MFMA (CIN=16 fp32 in, COUT=32, k-PAIRED, compensated hi/lo).
// ---------------------------------------------------------------------------
__global__ __launch_bounds__(256)
void sconv_mf0(const float* __restrict__ x, const _Float16* __restrict__ Wm0,
               const int* __restrict__ map, int Nout,
               _Float16* __restrict__ out, const float* __restrict__ zrow)
{
    const int lane = threadIdx.x & 63;
    const int wave = threadIdx.x >> 6;
    const int row0 = (blockIdx.x * 4 + wave) * 16;

    __shared__ int smap[4][16][28];

    int mk[16];
    bool anyv = false;
    #pragma unroll
    for (int r = 0; r < 16; ++r) {
        const int j = row0 + r;
        mk[r] = (lane < 27 && j < Nout) ? map[(size_t)lane * Nout + j] : -1;
        anyv |= (mk[r] >= 0);
    }
    unsigned long long act = __ballot(anyv);

    if (lane < 27) {
        #pragma unroll
        for (int r = 0; r < 16; ++r)
            smap[wave][r][lane] = mk[r];
    }

    f32x4 accH[2], accL[2];
    #pragma unroll
    for (int c = 0; c < 2; ++c) {
        accH[c] = (f32x4){0.f, 0.f, 0.f, 0.f};
        accL[c] = (f32x4){0.f, 0.f, 0.f, 0.f};
    }

    const int rrow = lane & 15;   // A row / D col
    const int kseg = lane >> 4;
    const int half = kseg & 1;    // cin half: 0 -> 0..7, 1 -> 8..15
    const bool useK1 = (kseg < 2);

    while (act) {
        const int k1 = (int)__builtin_ctzll(act);
        act &= act - 1;
        int k2 = -1;
        if (act) {
            k2 = (int)__builtin_ctzll(act);
            act &= act - 1;
        }
        const int ks = useK1 ? k1 : k2;
        int m = -1;
        if (ks >= 0) m = smap[wave][rrow][ks];

        const float* px = (m >= 0) ? (x + (size_t)m * 16 + half * 8)
                                   : (zrow + half * 8);
        const f4 x0 = *(const f4*)px;
        const f4 x1 = *(const f4*)(px + 4);
        h8 aH, aL;
        #pragma unroll
        for (int u = 0; u < 4; ++u) {
            const float v0 = x0[u], v1 = x1[u];
            const _Float16 h0 = (_Float16)v0;
            const _Float16 h1 = (_Float16)v1;
            aH[u]     = h0;
            aH[u + 4] = h1;
            aL[u]     = (_Float16)((v0 - (float)h0) * 2048.f);
            aL[u + 4] = (_Float16)((v1 - (float)h1) * 2048.f);
        }

        const int ksafe = (ks >= 0) ? ks : 0;   // a==0 makes b irrelevant
        const _Float16* wb = Wm0 + ((size_t)(ksafe * 2 + half) * 32) * 8;
        #pragma unroll
        for (int c = 0; c < 2; ++c) {
            const h8 b = *(const h8*)(wb + (size_t)(c * 16 + rrow) * 8);
            accH[c] = __builtin_amdgcn_mfma_f32_16x16x32_f16(aH, b, accH[c], 0, 0, 0);
            accL[c] = __builtin_amdgcn_mfma_f32_16x16x32_f16(aL, b, accL[c], 0, 0, 0);
        }
    }

    #pragma unroll
    for (int c = 0; c < 2; ++c) {
        #pragma unroll
        for (int r = 0; r < 4; ++r) {
            const int j = row0 + kseg * 4 + r;
            if (j < Nout)
                out[(size_t)j * 32 + c * 16 + rrow] =
                    (_Float16)(accH[c][r] + accL[c][r] * (1.f / 2048.f));
        }
    }
}

// ---------------------------------------------------------------------------
// MFMA sparse conv (UNGROUPED, raw map), round-8: one wave = 32 rows = TWO
// 16-row MFMA tiles sharing one k-union and the SAME B fragments (W L1
// traffic per row halves; 32 MFMAs per k-iter cover the next prefetch's
// ~300-cycle gather latency; per-wave setup amortized 2x). Used for block2.
// ---------------------------------------------------------------------------
template<int CIN, int CINA, int COUT>
__global__ __launch_bounds__(256)
void sconv_mf(const _Float16* __restrict__ xA, const _Float16* __restrict__ xB,
              const _Float16* __restrict__ Wm, const int* __restrict__ map,
              int Nout, _Float16* __restrict__ out,
              const _Float16* __restrict__ zrh)
{
    constexpr int CINB = CIN - CINA;
    constexpr int NT = CIN / 32;
    constexpr int NC = COUT / 16;
    static_assert(CINA % 32 == 0, "CINA must be a multiple of 32");
    const int lane = threadIdx.x & 63;
    const int wave = threadIdx.x >> 6;
    const int row0 = (blockIdx.x * 4 + wave) * 32;

    __shared__ int smap[4][32][28];

    bool anyv = false;
    #pragma unroll
    for (int r = 0; r < 32; ++r) {
        const int j = row0 + r;
        const int v = (lane < 27 && j < Nout) ? map[(size_t)lane * Nout + j] : -1;
        if (lane < 27) smap[wave][r][lane] = v;
        anyv |= (v >= 0);
    }
    unsigned long long act = __ballot(anyv) & 0x7FFFFFFull;

    f32x4 acc[2][NC];
    #pragma unroll
    for (int tt = 0; tt < 2; ++tt)
        #pragma unroll
        for (int c = 0; c < NC; ++c) acc[tt][c] = (f32x4){0.f, 0.f, 0.f, 0.f};

    const int rrow = lane & 15;
    const int kseg = lane >> 4;

    auto loada = [&](int k, h8 a[2][NT]) {
        #pragma unroll
        for (int tt = 0; tt < 2; ++tt) {
            const int m = smap[wave][tt * 16 + rrow][k];
            #pragma unroll
            for (int t = 0; t < NT; ++t) {
                const int cin0 = t * 32 + kseg * 8;
                const _Float16* pa;
                if (m >= 0) {
                    if (CINB > 0 && t * 32 >= CINA)
                        pa = xB + (size_t)m * CINB + (cin0 - CINA);
                    else
                        pa = xA + (size_t)m * CINA + cin0;
                } else {
                    pa = zrh;
                }
                a[tt][t] = *(const h8*)pa;
            }
        }
    };
    auto compute = [&](int k, h8 a[2][NT]) {
        const _Float16* Wk = Wm + ((size_t)k * NT * NC * 64 + lane) * 8;
        #pragma unroll
        for (int t = 0; t < NT; ++t) {
            #pragma unroll
            for (int c = 0; c < NC; ++c) {
                const h8 b = *(const h8*)(Wk + (size_t)(t * NC + c) * 64 * 8);
                acc[0][c] = __builtin_amdgcn_mfma_f32_16x16x32_f16(a[0][t], b, acc[0][c], 0, 0, 0);
                acc[1][c] = __builtin_amdgcn_mfma_f32_16x16x32_f16(a[1][t], b, acc[1][c], 0, 0, 0);
            }
        }
    };

    h8 aC[2][NT], aN[2][NT];
    int kC = -1;
    if (act) {
        kC = (int)__builtin_ctzll(act);
        act &= act - 1;
        loada(kC, aC);
    }
    while (kC >= 0) {
        int kN = -1;
        if (act) {
            kN = (int)__builtin_ctzll(act);
            act &= act - 1;
            loada(kN, aN);
        }
        compute(kC, aC);
        #pragma unroll
        for (int tt = 0; tt < 2; ++tt)
            #pragma unroll
            for (int t = 0; t < NT; ++t) aC[tt][t] = aN[tt][t];
        kC = kN;
    }

    #pragma unroll
    for (int tt = 0; tt < 2; ++tt) {
        #pragma unroll
        for (int c = 0; c < NC; ++c) {
            #pragma unroll
            for (int r = 0; r < 4; ++r) {
                const int j = row0 + tt * 16 + kseg * 4 + r;
                if (j < Nout)
                    out[(size_t)j * COUT + c * 16 + rrow] = (_Float16)acc[tt][c][r];
            }
        }
    }
}

// ---------------------------------------------------------------------------
// MFMA sparse conv (GROUPED), round-8: 32 order slots/wave, two 16-row MFMA
// tiles sharing the class k-union and B fragments. Fully-dead waves (all
// order slots -1: class-region tail padding) exit after the first ballot,
// BEFORE any LDS staging.
// ---------------------------------------------------------------------------
template<int CIN, int CINA, int COUT>
__global__ __launch_bounds__(256)
void sconv_mf_g(const _Float16* __restrict__ xA, const _Float16* __restrict__ xB,
                const _Float16* __restrict__ Wm, const int* __restrict__ mapT,
                const int* __restrict__ order, int NTOT, int Nout,
                _Float16* __restrict__ out, const _Float16* __restrict__ zrh)
{
    constexpr int CINB = CIN - CINA;
    constexpr int NT = CIN / 32;
    constexpr int NC = COUT / 16;
    static_assert(CINA % 32 == 0, "CINA must be a multiple of 32");
    const int lane = threadIdx.x & 63;
    const int wave = threadIdx.x >> 6;
    const int wrow0 = (blockIdx.x * 4 + wave) * 32;

    __shared__ int sjr[4][32];
    __shared__ int smap[4][32][28];

    int jreg = -1;
    if (lane < 32) {
        const int idx = wrow0 + lane;
        if (idx < NTOT) jreg = order[idx];
    }
    if (!__ballot(jreg >= 0)) return;     // dead wave: region tail padding
    if (lane < 32) sjr[wave][lane] = jreg;

    bool anyv = false;
    #pragma unroll
    for (int r = 0; r < 32; ++r) {
        const int jr = sjr[wave][r];      // wave-local LDS RAW (lgkmcnt)
        int v = -1;
        if (jr >= 0 && lane < 27) v = mapT[(size_t)jr * 32 + lane];
        if (lane < 27) smap[wave][r][lane] = v;
        anyv |= (v >= 0);
    }
    unsigned long long act = __ballot(anyv) & 0x7FFFFFFull;

    f32x4 acc[2][NC];
    #pragma unroll
    for (int tt = 0; tt < 2; ++tt)
        #pragma unroll
        for (int c = 0; c < NC; ++c) acc[tt][c] = (f32x4){0.f, 0.f, 0.f, 0.f};

    const int rrow = lane & 15;
    const int kseg = lane >> 4;

    auto loada = [&](int k, h8 a[2][NT]) {
        #pragma unroll
        for (int tt = 0; tt < 2; ++tt) {
            const int m = smap[wave][tt * 16 + rrow][k];
            #pragma unroll
            for (int t = 0; t < NT; ++t) {
                const int cin0 = t * 32 + kseg * 8;
                const _Float16* pa;
                if (m >= 0) {
                    if (CINB > 0 && t * 32 >= CINA)
                        pa = xB + (size_t)m * CINB + (cin0 - CINA);
                    else
                        pa = xA + (size_t)m * CINA + cin0;
                } else {
                    pa = zrh;
                }
                a[tt][t] = *(const h8*)pa;
            }
        }
    };
    auto compute = [&](int k, h8 a[2][NT]) {
        const _Float16* Wk = Wm + ((size_t)k * NT * NC * 64 + lane) * 8;
        #pragma unroll
        for (int t = 0; t < NT; ++t) {
            #pragma unroll
            for (int c = 0; c < NC; ++c) {
                const h8 b = *(const h8*)(Wk + (size_t)(t * NC + c) * 64 * 8);
                acc[0][c] = __builtin_amdgcn_mfma_f32_16x16x32_f16(a[0][t], b, acc[0][c], 0, 0, 0);
                acc[1][c] = __builtin_amdgcn_mfma_f32_16x16x32_f16(a[1][t], b, acc[1][c], 0, 0, 0);
            }
        }
    };

    h8 aC[2][NT], aN[2][NT];
    int kC = -1;
    if (act) {
        kC = (int)__builtin_ctzll(act);
        act &= act - 1;
        loada(kC, aC);
    }
    while (kC >= 0) {
        int kN = -1;
        if (act) {
            kN = (int)__builtin_ctzll(act);
            act &= act - 1;
            loada(kN, aN);
        }
        compute(kC, aC);
        #pragma unroll
        for (int tt = 0; tt < 2; ++tt)
            #pragma unroll
            for (int t = 0; t < NT; ++t) aC[tt][t] = aN[tt][t];
        kC = kN;
    }

    #pragma unroll
    for (int tt = 0; tt < 2; ++tt) {
        #pragma unroll
        for (int c = 0; c < NC; ++c) {
            #pragma unroll
            for (int r = 0; r < 4; ++r) {
                const int j = sjr[wave][tt * 16 + kseg * 4 + r];
                if (j >= 0)
                    out[(size_t)j * COUT + c * 16 + rrow] = (_Float16)acc[tt][c][r];
            }
        }
    }
}

// ---------------------------------------------------------------------------
// conv0t: concat(d1[*,64]h, s1[*,32]h) -> out[N0,2] fp32. ctz-union loop.
// ---------------------------------------------------------------------------
__global__ __launch_bounds__(256)
void sconv0t(const _Float16* __restrict__ d1, const _Float16* __restrict__ s1,
             const float* __restrict__ W /*[27,96,2]*/,
             const int* __restrict__ map, int N, float* __restrict__ out,
             const _Float16* __restrict__ zrh)
{
    const int tid  = threadIdx.x;
    const int lane = tid & 63;
    const int l32  = tid & 31;
    const int j    = blockIdx.x * 8 + (tid >> 5);

    int mk = (l32 < 27 && j < N) ? map[(size_t)l32 * N + j] : -1;
    const unsigned long long bal = __ballot(mk >= 0);
    unsigned int act = (unsigned int)((bal | (bal >> 32)) & 0x7FFFFFFu);

    float a0 = 0.f, a1 = 0.f;
    while (act) {
        const int k = (int)__builtin_ctz(act);
        act &= act - 1;
        const int m = __shfl(mk, (lane & 32) + k);
        const _Float16* p1 = (m >= 0) ? (d1 + (size_t)m * 64) : zrh;
        const _Float16* p2 = (m >= 0) ? (s1 + (size_t)m * 32) : zrh;
        const float* w = W + (size_t)k * 96 * 2;
        const float x0 = (float)p1[l32];
        const float x1 = (float)p1[l32 + 32];
        const float x2 = (float)p2[l32];
        a0 = fmaf(x0, w[l32 * 2 + 0], a0);
        a1 = fmaf(x0, w[l32 * 2 + 1], a1);
        a0 = fmaf(x1, w[(l32 + 32) * 2 + 0], a0);
        a1 = fmaf(x1, w[(l32 + 32) * 2 + 1], a1);
        a0 = fmaf(x2, w[(l32 + 64) * 2 + 0], a0);
        a1 = fmaf(x2, w[(l32 + 64) * 2 + 1], a1);
    }
    #pragma unroll
    for (int off = 1; off < 32; off <<= 1) {
        a0 += __shfl_xor(a0, off, 32);
        a1 += __shfl_xor(a1, off, 32);
    }
    if (l32 == 0 && j < N) {
        out[(size_t)j * 2 + 0] = a0;
        out[(size_t)j * 2 + 1] = a1;
    }
}

// ---------------------------------------------------------------------------
// BN pass 1 on half tensors
// ---------------------------------------------------------------------------
template<int C>
__global__ __launch_bounds__(256)
void bn_reduce_h(const _Float16* __restrict__ x, int N,
                 float* __restrict__ sums)
{
    constexpr int RG = 256 / C;
    const int tid = threadIdx.x;
    const int c   = tid % C;
    const int rg  = tid / C;
    float s = 0.f, s2 = 0.f;
    for (int j = blockIdx.x * RG + rg; j < N; j += gridDim.x * RG) {
        const float v = (float)x[(size_t)j * C + c];
        s += v;
        s2 += v * v;
    }
    __shared__ float sh[2 * 256];
    sh[tid] = s;
    sh[256 + tid] = s2;
    __syncthreads();
    for (int stride = 128; stride >= C; stride >>= 1) {
        if (tid < stride) {
            sh[tid] += sh[tid + stride];
            sh[256 + tid] += sh[256 + tid + stride];
        }
        __syncthreads();
    }
    if (tid < C) {
        atomicAdd(&sums[c], sh[tid]);
        atomicAdd(&sums[C + c], sh[256 + tid]);
    }
}

// ---------------------------------------------------------------------------
// BN pass 2 on half tensors
// ---------------------------------------------------------------------------
template<int C>
__global__ __launch_bounds__(256)
void bn_apply_h(_Float16* __restrict__ x, int N,
                const float* __restrict__ sums,
                const float* __restrict__ g, const float* __restrict__ b)
{
    const int tid = blockIdx.x * blockDim.x + threadIdx.x;
    const int c = tid % C;
    const float invN = 1.0f / (float)N;
    const float mean = sums[c] * invN;
    float var = sums[C + c] * invN - mean * mean;
    var = fmaxf(var, 0.f);
    const float sc = g[c] * rsqrtf(var + BN_EPS);
    const float sh = b[c] - mean * sc;
    const int rows_stride = (gridDim.x * blockDim.x) / C;
    for (int j = tid / C; j < N; j += rows_stride) {
        const size_t i = (size_t)j * C + c;
        const float v = fmaf((float)x[i], sc, sh);
        x[i] = (_Float16)(v > 0.f ? v : 0.f);
    }
}

// ---------------------------------------------------------------------------
extern "C" void kernel_launch(void* const* d_in, const int* in_sizes, int n_in,
                              void* d_out, int out_size, void* d_ws, size_t ws_size,
                              hipStream_t stream)
{
    const float* feats = (const float*)d_in[0];
    const float* W0  = (const float*)d_in[1];
    const float* g0  = (const float*)d_in[2];
    const float* b0  = (const float*)d_in[3];
    const float* W1  = (const float*)d_in[4];
    const float* g1  = (const float*)d_in[5];
    const float* b1  = (const float*)d_in[6];
    const float* W2  = (const float*)d_in[7];
    const float* g2  = (const float*)d_in[8];
    const float* b2  = (const float*)d_in[9];
    const float* W2t = (const float*)d_in[10];
    const float* g2t = (const float*)d_in[11];
    const float* b2t = (const float*)d_in[12];
    const float* W1t = (const float*)d_in[13];
    const float* g1t = (const float*)d_in[14];
    const float* b1t = (const float*)d_in[15];
    const float* W0t = (const float*)d_in[16];
    const int* map0  = (const int*)d_in[17];
    const int* map1  = (const int*)d_in[18];
    const int* map2  = (const int*)d_in[19];
    const int* map2t = (const int*)d_in[20];
    const int* map1t = (const int*)d_in[21];
    const int* map0t = (const int*)d_in[22];

    const int N0 = in_sizes[0] / 16;
    const int N1 = in_sizes[18] / 27;
    const int N2 = in_sizes[19] / 27;

    const int Npad0 = (N0 + 15) & ~15;
    const int Npad1 = (N1 + 15) & ~15;

    float* ws = (float*)d_ws;
    float* sums  = ws;          // 704 floats of BN accumulators
    float* sums0 = sums;        // 2*32
    float* sums1 = sums + 64;   // 2*64
    float* sums2 = sums + 192;  // 2*128
    float* sums3 = sums + 448;  // 2*64
    float* sums4 = sums + 576;  // 2*64
    float* zrow  = sums + 704;  // 128 zeroed floats (fp32 & f16 zero rows)
    int*   gcnt  = (int*)(zrow + 128);  // 64 ints: 2x gcursor[9] regions
    _Float16* Wm0h = (_Float16*)(gcnt + 64);    // 27*2*32*8 f16 (paired MFMA)
    _Float16* Wh1  = Wm0h + 27 * 2 * 32 * 8;    // 27*32*64  (r1 layout)
    _Float16* Wh2  = Wh1 + 27 * 32 * 64;        // 27*64*128  (MFMA layout)
    _Float16* Wh2t = Wh2 + 27 * 64 * 128;       // 27*128*64  (MFMA layout)
    _Float16* Wh1t = Wh2t + 27 * 128 * 64;      // 27*128*64  (MFMA layout)
    _Float16* y0 = Wh1t + 27 * 128 * 64;        // [N0,32]  s1
    _Float16* y1 = y0 + (size_t)N0 * 32;        // [N1,64]  s2
    _Float16* y2 = y1 + (size_t)N1 * 64;        // [N2,128] s4
    _Float16* y3 = y2 + (size_t)N2 * 128;       // [N1,64]  d2
    _Float16* y4 = y3 + (size_t)N1 * 64;        // [N0,64]  d1
    int* mapT = (int*)(y4 + (size_t)N0 * 64);   // [Nmax,32] transposed map
    int* orderA = mapT + (size_t)N0 * 32;       // [9*Npad1] block2_tr groups
    int* orderB = orderA + (size_t)9 * Npad1;   // [9*Npad0] block1_tr groups
    const _Float16* zrh = (const _Float16*)zrow;

    (void)hipMemsetAsync(sums, 0, (704 + 128 + 64) * sizeof(float), stream);
    (void)hipMemsetAsync(orderA, 0xFF,
                         (size_t)9 * (Npad1 + Npad0) * sizeof(int), stream);

    // weight transposes (tiny)
    wtrans_mf0<<<(27 * 2 * 32 + 255) / 256, 256, 0, stream>>>(W0, Wm0h);
    wtrans_h<32, 64><<<(27 * 4 * 64 + 255) / 256, 256, 0, stream>>>(W1, Wh1);
    wtrans_mf<64, 128><<<(27 * 2 * 8 * 64 + 255) / 256, 256, 0, stream>>>(W2, Wh2);
    wtrans_mf<128, 64><<<(27 * 4 * 4 * 64 + 255) / 256, 256, 0, stream>>>(W2t, Wh2t);
    wtrans_mf<128, 64><<<(27 * 4 * 4 * 64 + 255) / 256, 256, 0, stream>>>(W1t, Wh1t);

    // block0: feats[N0,16] fp32 -> y0[N0,32] half. MFMA k-paired hi/lo.
    sconv_mf0<<<(N0 + 63) / 64, 256, 0, stream>>>(
        feats, Wm0h, map0, N0, y0, zrow);
    bn_reduce_h<32><<<256, 256, 0, stream>>>(y0, N0, sums0);
    bn_apply_h<32><<<512, 256, 0, stream>>>(y0, N0, sums0, g0, b0);

    // block1 (SPARSE map, ~1.3 k/row): one wave per row (scalar dot2 path)
    map_transpose<<<(N1 + 255) / 256, 256, 0, stream>>>(map1, N1, mapT);
    sconv_r1<32, 32, 64><<<(N1 + 3) / 4, 256, 0, stream>>>(
        y0, nullptr, Wh1, mapT, N1, y1);
    bn_reduce_h<64><<<256, 256, 0, stream>>>(y1, N1, sums1);
    bn_apply_h<64><<<512, 256, 0, stream>>>(y1, N1, sums1, g1, b1);

    // block2: MFMA ungrouped, 32 rows/wave
    sconv_mf<64, 64, 128><<<(N2 + 127) / 128, 256, 0, stream>>>(
        y1, nullptr, Wh2, map2, N2, y2, zrh);
    bn_reduce_h<128><<<256, 256, 0, stream>>>(y2, N2, sums2);
    bn_apply_h<128><<<512, 256, 0, stream>>>(y2, N2, sums2, g2, b2);

    // block2_tr: parity-grouped MFMA, 32 rows/wave
    map_transpose_grp<<<(N1 + 255) / 256, 256, 0, stream>>>(
        map2t, N1, Npad1, mapT, gcnt, orderA);
    sconv_mf_g<128, 128, 64><<<(9 * Npad1 + 127) / 128, 256, 0, stream>>>(
        y2, nullptr, Wh2t, mapT, orderA, 9 * Npad1, N1, y3, zrh);
    bn_reduce_h<64><<<256, 256, 0, stream>>>(y3, N1, sums3);
    bn_apply_h<64><<<512, 256, 0, stream>>>(y3, N1, sums3, g2t, b2t);

    // block1_tr: parity-grouped MFMA, 32 rows/wave, concat (y3[64] ++ y1[64])
    map_transpose_grp<<<(N0 + 255) / 256, 256, 0, stream>>>(
        map1t, N0, Npad0, mapT, gcnt + 32, orderB);
    sconv_mf_g<128, 64, 64><<<(9 * Npad0 + 127) / 128, 256, 0, stream>>>(
        y3, y1, Wh1t, mapT, orderB, 9 * Npad0, N0, y4, zrh);
    bn_reduce_h<64><<<256, 256, 0, stream>>>(y4, N0, sums4);
    bn_apply_h<64><<<512, 256, 0, stream>>>(y4, N0, sums4, g1t, b1t);

    // block0_tr: concat(d1,s1)[N0,96] -> out[N0,2] fp32
    sconv0t<<<(N0 + 7) / 8, 256, 0, stream>>>(y4, y0, W0t, map0t, N0,
                                              (float*)d_out, zrh);
}